// Round 1
// baseline (3528.950 us; speedup 1.0000x reference)
//
#include <hip/hip_runtime.h>
#include <hip/hip_bf16.h>
#include <math.h>

// ---------------- constants ----------------
#define BB 16
#define HH 64
#define WW_ 64
#define CC 192
#define WSZ 16
#define SHIFT 8
#define NH 6
#define DD 32
#define NN 256       // tokens per window
#define HID 768
#define NWIN 256     // B * 16 windows
// ws byte offsets
#define OFF_TBL   0
#define OFF_BIAS  (32ll*1024)
#define OFF_Q     (2ll*1024*1024)
#define OFF_K     (28ll*1024*1024)
#define OFF_V     (56ll*1024*1024)
#define OFF_AO    (84ll*1024*1024)

__device__ __forceinline__ float cpb_coord(int u) {
    // u in [-15,15]: t = u*8/15; sign(t)*log2(|t|+1)/log2(8)
    float t = (float)u * (8.0f / 15.0f);
    return copysignf(log2f(fabsf(t) + 1.0f) * (1.0f / 3.0f), t);
}

// ---------------- CPB table MLP: tbl[m][h], m in [0,961) ----------------
__global__ __launch_bounds__(512) void k_tbl(
    const float* __restrict__ w1, const float* __restrict__ b1,
    const float* __restrict__ w2, float* __restrict__ tbl)
{
    __shared__ float r[512];
    int m = blockIdx.x;            // 0..960
    int a = m / 31, b = m % 31;
    float c0 = cpb_coord(a - 15);
    float c1 = cpb_coord(b - 15);
    int hd = threadIdx.x;          // 0..511
    float rv = c0 * w1[hd * 2 + 0] + c1 * w1[hd * 2 + 1] + b1[hd];
    r[hd] = fmaxf(rv, 0.0f);
    __syncthreads();
    if (hd < NH) {
        float s = 0.0f;
        for (int k = 0; k < 512; ++k) s += r[k] * w2[hd * 512 + k];
        tbl[m * NH + hd] = s;
    }
}

// ---------------- bias16[h][i][j] = 16*sigmoid(tbl[relidx(i,j)][h]) ----------------
__global__ __launch_bounds__(256) void k_bias(
    const float* __restrict__ tbl, float* __restrict__ bias16)
{
    int h = blockIdx.x >> 8;
    int i = blockIdx.x & 255;
    int j = threadIdx.x;
    int yi = i >> 4, xi = i & 15, yj = j >> 4, xj = j & 15;
    int idx = (yi - yj + 15) * 31 + (xi - xj + 15);
    float v = tbl[idx * NH + h];
    bias16[((size_t)h * NN + i) * NN + j] = 16.0f / (1.0f + __expf(-v));
}

// ---------------- QKV: gather(roll+window) + 3 GEMMs + q/k norm ----------------
__global__ __launch_bounds__(256) void k_qkv(
    const float* __restrict__ x,
    const float* __restrict__ q_w, const float* __restrict__ q_b,
    const float* __restrict__ k_w,
    const float* __restrict__ v_w, const float* __restrict__ v_b,
    __hip_bfloat16* __restrict__ qn, __hip_bfloat16* __restrict__ kn,
    __hip_bfloat16* __restrict__ vv)
{
    __shared__ float xs[32][193];
    __shared__ float wt[32][193];
    __shared__ float out[32][193];
    __shared__ float rnorm[32][6];
    int tid = threadIdx.x;
    int rbase = blockIdx.x * 32;

    for (int idx = tid; idx < 32 * CC; idx += 256) {
        int t = idx / CC, c = idx % CC;
        int r = rbase + t;
        int win = r >> 8, n = r & 255;
        int b = win >> 4, wh = (win >> 2) & 3, ww = win & 3;
        int yi = n >> 4, xi = n & 15;
        int sy = (wh * 16 + yi + SHIFT) & 63;
        int sx = (ww * 16 + xi + SHIFT) & 63;
        xs[t][c] = x[((size_t)b * 4096 + sy * 64 + sx) * CC + c];
    }
    __syncthreads();

    for (int m = 0; m < 3; ++m) {
        const float* W  = (m == 0) ? q_w : (m == 1) ? k_w : v_w;
        const float* Bv = (m == 0) ? q_b : (m == 2) ? v_b : nullptr;
        for (int ocb = 0; ocb < CC; ocb += 32) {
            for (int idx = tid; idx < 32 * CC; idx += 256) {
                int o = idx / CC, c = idx % CC;
                wt[o][c] = W[(ocb + o) * CC + c];
            }
            __syncthreads();
            int tg = tid >> 4, og = tid & 15;
            int t0 = 2 * tg, t1 = t0 + 1, o0 = 2 * og, o1 = o0 + 1;
            float a00 = 0, a01 = 0, a10 = 0, a11 = 0;
            #pragma unroll 8
            for (int c = 0; c < CC; ++c) {
                float x0 = xs[t0][c], x1 = xs[t1][c];
                float w0 = wt[o0][c], w1 = wt[o1][c];
                a00 += x0 * w0; a01 += x0 * w1; a10 += x1 * w0; a11 += x1 * w1;
            }
            float bb0 = Bv ? Bv[ocb + o0] : 0.0f;
            float bb1 = Bv ? Bv[ocb + o1] : 0.0f;
            out[t0][ocb + o0] = a00 + bb0; out[t0][ocb + o1] = a01 + bb1;
            out[t1][ocb + o0] = a10 + bb0; out[t1][ocb + o1] = a11 + bb1;
            __syncthreads();
        }
        if (m < 2) {
            if (tid < 32 * NH) {
                int t = tid / NH, h = tid % NH;
                float s = 0.0f;
                #pragma unroll
                for (int d = 0; d < DD; ++d) { float v = out[t][h * DD + d]; s += v * v; }
                rnorm[t][h] = rsqrtf(s);
            }
        }
        __syncthreads();
        __hip_bfloat16* dst = (m == 0) ? qn : (m == 1) ? kn : vv;
        for (int idx = tid; idx < 32 * CC; idx += 256) {
            int t = idx / CC, c = idx % CC;
            int h = c >> 5, d = c & 31;
            float v = out[t][c];
            if (m < 2) v *= rnorm[t][h];
            int r = rbase + t;
            int win = r >> 8, n = r & 255;
            dst[(((size_t)win * NH + h) * NN + n) * DD + d] = __float2bfloat16(v);
        }
        __syncthreads();
    }
}

// ---------------- attention: one block per (window, head), flash-style ----------------
__global__ __launch_bounds__(256) void k_attn(
    const __hip_bfloat16* __restrict__ qn,
    const __hip_bfloat16* __restrict__ kn,
    const __hip_bfloat16* __restrict__ vv,
    const float* __restrict__ bias16,
    const float* __restrict__ logit_scale,
    __hip_bfloat16* __restrict__ ao)
{
    int wh_ = blockIdx.x;
    int win = wh_ / NH, h = wh_ % NH;
    int wwh = (win >> 2) & 3, www = win & 3;
    int i = threadIdx.x;                       // q row
    float scale = __expf(fminf(logit_scale[h], 4.6051702f));

    float q[DD];
    const __hip_bfloat16* qp = qn + (((size_t)win * NH + h) * NN + i) * DD;
    #pragma unroll
    for (int d = 0; d < DD; ++d) q[d] = __bfloat162float(qp[d]);

    int yi = i >> 4, xi = i & 15;
    int rhi = (wwh < 3) ? 0 : ((yi < SHIFT) ? 1 : 2);
    int rwi = (www < 3) ? 0 : ((xi < SHIFT) ? 1 : 2);
    int cnti = rhi * 3 + rwi;
    bool masked_win = (wwh == 3) || (www == 3);

    __shared__ float ks[32][33];
    __shared__ float vs[32][33];
    __shared__ float bs[256][33];

    float m = -1e30f, l = 0.0f;
    float acc[DD];
    #pragma unroll
    for (int d = 0; d < DD; ++d) acc[d] = 0.0f;

    const __hip_bfloat16* kbase = kn + (((size_t)win * NH + h) * NN) * DD;
    const __hip_bfloat16* vbase = vv + (((size_t)win * NH + h) * NN) * DD;
    const float* bbase = bias16 + ((size_t)h * NN + i) * NN;

    for (int jc = 0; jc < NN; jc += 32) {
        __syncthreads();
        for (int idx = i; idx < 32 * DD; idx += 256) {
            int jj = idx >> 5, d = idx & 31;
            ks[jj][d] = __bfloat162float(kbase[(jc + jj) * DD + d]);
            vs[jj][d] = __bfloat162float(vbase[(jc + jj) * DD + d]);
        }
        #pragma unroll
        for (int jj = 0; jj < 32; ++jj) bs[i][jj] = bbase[jc + jj];
        __syncthreads();
        for (int jj = 0; jj < 32; ++jj) {
            int j = jc + jj;
            float s = 0.0f;
            #pragma unroll
            for (int d = 0; d < DD; ++d) s += q[d] * ks[jj][d];
            s = s * scale + bs[i][jj];
            if (masked_win) {
                int yj = j >> 4, xj = j & 15;
                int rhj = (wwh < 3) ? 0 : ((yj < SHIFT) ? 1 : 2);
                int rwj = (www < 3) ? 0 : ((xj < SHIFT) ? 1 : 2);
                if (cnti != rhj * 3 + rwj) s -= 100.0f;
            }
            float mn = fmaxf(m, s);
            float corr = __expf(m - mn);
            float p = __expf(s - mn);
            l = l * corr + p;
            #pragma unroll
            for (int d = 0; d < DD; ++d) acc[d] = acc[d] * corr + p * vs[jj][d];
            m = mn;
        }
    }
    float rl = 1.0f / l;
    __hip_bfloat16* aop = ao + ((size_t)win * NN + i) * CC + h * DD;
    #pragma unroll
    for (int d = 0; d < DD; ++d) aop[d] = __float2bfloat16(acc[d] * rl);
}

// ---------------- proj + window-reverse + unroll + cond-LN1 residual ----------------
__global__ __launch_bounds__(256) void k_proj(
    const __hip_bfloat16* __restrict__ ao,
    const float* __restrict__ proj_w, const float* __restrict__ proj_b,
    const float* __restrict__ x, const float* __restrict__ time,
    const float* __restrict__ ww, const float* __restrict__ wb,
    const float* __restrict__ bw, const float* __restrict__ bb,
    float* __restrict__ hout)
{
    __shared__ float xs[32][193];
    __shared__ float wt[32][193];
    __shared__ float out[32][193];
    __shared__ float mv[32][2];
    int tid = threadIdx.x;
    int rbase = blockIdx.x * 32;

    for (int idx = tid; idx < 32 * CC; idx += 256) {
        int t = idx / CC, c = idx % CC;
        int r = rbase + t;
        int b = r >> 12, p = r & 4095;
        int y = p >> 6, xc = p & 63;
        int gy = (y + 64 - SHIFT) & 63, gx = (xc + 64 - SHIFT) & 63;
        int win = (b << 4) + ((gy >> 4) << 2) + (gx >> 4);
        int n = ((gy & 15) << 4) + (gx & 15);
        xs[t][c] = __bfloat162float(ao[((size_t)win * NN + n) * CC + c]);
    }
    __syncthreads();
    for (int ocb = 0; ocb < CC; ocb += 32) {
        for (int idx = tid; idx < 32 * CC; idx += 256) {
            int o = idx / CC, c = idx % CC;
            wt[o][c] = proj_w[(ocb + o) * CC + c];
        }
        __syncthreads();
        int tg = tid >> 4, og = tid & 15;
        int t0 = 2 * tg, t1 = t0 + 1, o0 = 2 * og, o1 = o0 + 1;
        float a00 = 0, a01 = 0, a10 = 0, a11 = 0;
        #pragma unroll 8
        for (int c = 0; c < CC; ++c) {
            float x0 = xs[t0][c], x1 = xs[t1][c];
            float w0 = wt[o0][c], w1 = wt[o1][c];
            a00 += x0 * w0; a01 += x0 * w1; a10 += x1 * w0; a11 += x1 * w1;
        }
        out[t0][ocb + o0] = a00 + proj_b[ocb + o0];
        out[t0][ocb + o1] = a01 + proj_b[ocb + o1];
        out[t1][ocb + o0] = a10 + proj_b[ocb + o0];
        out[t1][ocb + o1] = a11 + proj_b[ocb + o1];
        __syncthreads();
    }
    if (tid < 32) {
        float s = 0, s2 = 0;
        for (int c = 0; c < CC; ++c) { float v = out[tid][c]; s += v; s2 += v * v; }
        float mean = s / (float)CC, var = s2 / (float)CC - mean * mean;
        mv[tid][0] = mean; mv[tid][1] = rsqrtf(var + 1e-5f);
    }
    __syncthreads();
    for (int idx = tid; idx < 32 * CC; idx += 256) {
        int t = idx / CC, c = idx % CC;
        int r = rbase + t;
        float tm = time[r >> 12];
        float w_ = tm * ww[c] + wb[c];
        float b_ = tm * bw[c] + bb[c];
        float xn = (out[t][c] - mv[t][0]) * mv[t][1];
        hout[(size_t)r * CC + c] = x[(size_t)r * CC + c] + w_ * xn + b_;
    }
}

// ---------------- MLP (fc1+gelu+fc2) + cond-LN2 residual, in-place on d_out ----------------
__global__ __launch_bounds__(256) void k_mlp(
    float* __restrict__ hio,
    const float* __restrict__ fc1_w, const float* __restrict__ fc1_b,
    const float* __restrict__ fc2_w, const float* __restrict__ fc2_b,
    const float* __restrict__ time,
    const float* __restrict__ ww, const float* __restrict__ wb,
    const float* __restrict__ bw, const float* __restrict__ bb)
{
    __shared__ float hs[16][193];
    __shared__ float wt[64][193];
    __shared__ float h2[16][769];
    __shared__ float out[16][193];
    __shared__ float mv[16][2];
    int tid = threadIdx.x;
    int rbase = blockIdx.x * 16;

    for (int idx = tid; idx < 16 * CC; idx += 256) {
        int t = idx / CC, c = idx % CC;
        hs[t][c] = hio[(size_t)(rbase + t) * CC + c];
    }
    __syncthreads();

    int tg = tid >> 5;                 // 0..7 -> tokens 2tg,2tg+1
    int og = tid & 31;                 // -> oc 2og,2og+1 within 64-chunk
    int t0 = 2 * tg, t1 = t0 + 1;

    // fc1 + exact gelu
    for (int ocb = 0; ocb < HID; ocb += 64) {
        for (int idx = tid; idx < 64 * CC; idx += 256) {
            int o = idx / CC, c = idx % CC;
            wt[o][c] = fc1_w[(ocb + o) * CC + c];
        }
        __syncthreads();
        int o0 = 2 * og, o1 = o0 + 1;
        float a00 = 0, a01 = 0, a10 = 0, a11 = 0;
        #pragma unroll 8
        for (int c = 0; c < CC; ++c) {
            float x0 = hs[t0][c], x1 = hs[t1][c];
            float w0 = wt[o0][c], w1 = wt[o1][c];
            a00 += x0 * w0; a01 += x0 * w1; a10 += x1 * w0; a11 += x1 * w1;
        }
        a00 += fc1_b[ocb + o0]; a01 += fc1_b[ocb + o1];
        a10 += fc1_b[ocb + o0]; a11 += fc1_b[ocb + o1];
        h2[t0][ocb + o0] = 0.5f * a00 * (1.0f + erff(a00 * 0.70710678f));
        h2[t0][ocb + o1] = 0.5f * a01 * (1.0f + erff(a01 * 0.70710678f));
        h2[t1][ocb + o0] = 0.5f * a10 * (1.0f + erff(a10 * 0.70710678f));
        h2[t1][ocb + o1] = 0.5f * a11 * (1.0f + erff(a11 * 0.70710678f));
        __syncthreads();
    }

    // fc2 (K=768 in 4 chunks of 192)
    for (int ocb = 0; ocb < CC; ocb += 64) {
        int o0 = 2 * og, o1 = o0 + 1;
        float a00 = 0, a01 = 0, a10 = 0, a11 = 0;
        for (int kb = 0; kb < HID; kb += CC) {
            for (int idx = tid; idx < 64 * CC; idx += 256) {
                int o = idx / CC, c = idx % CC;
                wt[o][c] = fc2_w[(ocb + o) * HID + kb + c];
            }
            __syncthreads();
            #pragma unroll 8
            for (int c = 0; c < CC; ++c) {
                float x0 = h2[t0][kb + c], x1 = h2[t1][kb + c];
                float w0 = wt[o0][c], w1 = wt[o1][c];
                a00 += x0 * w0; a01 += x0 * w1; a10 += x1 * w0; a11 += x1 * w1;
            }
            __syncthreads();
        }
        out[t0][ocb + o0] = a00 + fc2_b[ocb + o0];
        out[t0][ocb + o1] = a01 + fc2_b[ocb + o1];
        out[t1][ocb + o0] = a10 + fc2_b[ocb + o0];
        out[t1][ocb + o1] = a11 + fc2_b[ocb + o1];
    }
    __syncthreads();
    if (tid < 16) {
        float s = 0, s2 = 0;
        for (int c = 0; c < CC; ++c) { float v = out[tid][c]; s += v; s2 += v * v; }
        float mean = s / (float)CC, var = s2 / (float)CC - mean * mean;
        mv[tid][0] = mean; mv[tid][1] = rsqrtf(var + 1e-5f);
    }
    __syncthreads();
    for (int idx = tid; idx < 16 * CC; idx += 256) {
        int t = idx / CC, c = idx % CC;
        float tm = time[(rbase + t) >> 12];
        float w_ = tm * ww[c] + wb[c];
        float b_ = tm * bw[c] + bb[c];
        float xn = (out[t][c] - mv[t][0]) * mv[t][1];
        hio[(size_t)(rbase + t) * CC + c] = hs[t][c] + w_ * xn + b_;
    }
}

extern "C" void kernel_launch(void* const* d_in, const int* in_sizes, int n_in,
                              void* d_out, int out_size, void* d_ws, size_t ws_size,
                              hipStream_t stream)
{
    const float* x        = (const float*)d_in[0];
    const float* time     = (const float*)d_in[1];
    const float* q_w      = (const float*)d_in[2];
    const float* q_b      = (const float*)d_in[3];
    const float* k_w      = (const float*)d_in[4];
    const float* v_w      = (const float*)d_in[5];
    const float* v_b      = (const float*)d_in[6];
    const float* lscale   = (const float*)d_in[7];
    const float* cpb_w1   = (const float*)d_in[8];
    const float* cpb_b1   = (const float*)d_in[9];
    const float* cpb_w2   = (const float*)d_in[10];
    const float* proj_w   = (const float*)d_in[11];
    const float* proj_b   = (const float*)d_in[12];
    const float* ln1_ww   = (const float*)d_in[13];
    const float* ln1_wb   = (const float*)d_in[14];
    const float* ln1_bw   = (const float*)d_in[15];
    const float* ln1_bb   = (const float*)d_in[16];
    const float* fc1_w    = (const float*)d_in[17];
    const float* fc1_b    = (const float*)d_in[18];
    const float* fc2_w    = (const float*)d_in[19];
    const float* fc2_b    = (const float*)d_in[20];
    const float* ln2_ww   = (const float*)d_in[21];
    const float* ln2_wb   = (const float*)d_in[22];
    const float* ln2_bw   = (const float*)d_in[23];
    const float* ln2_bb   = (const float*)d_in[24];

    char* ws = (char*)d_ws;
    float* tbl            = (float*)(ws + OFF_TBL);
    float* bias16         = (float*)(ws + OFF_BIAS);
    __hip_bfloat16* qn    = (__hip_bfloat16*)(ws + OFF_Q);
    __hip_bfloat16* kn    = (__hip_bfloat16*)(ws + OFF_K);
    __hip_bfloat16* vv    = (__hip_bfloat16*)(ws + OFF_V);
    __hip_bfloat16* ao    = (__hip_bfloat16*)(ws + OFF_AO);
    float* out            = (float*)d_out;

    k_tbl <<<961, 512, 0, stream>>>(cpb_w1, cpb_b1, cpb_w2, tbl);
    k_bias<<<NH * NN, 256, 0, stream>>>(tbl, bias16);
    k_qkv <<<(NWIN * NN) / 32, 256, 0, stream>>>(x, q_w, q_b, k_w, v_w, v_b, qn, kn, vv);
    k_attn<<<NWIN * NH, 256, 0, stream>>>(qn, kn, vv, bias16, lscale, ao);
    k_proj<<<(BB * 4096) / 32, 256, 0, stream>>>(ao, proj_w, proj_b, x, time,
                                                 ln1_ww, ln1_wb, ln1_bw, ln1_bb, out);
    k_mlp <<<(BB * 4096) / 16, 256, 0, stream>>>(out, fc1_w, fc1_b, fc2_w, fc2_b, time,
                                                 ln2_ww, ln2_wb, ln2_bw, ln2_bb);
}

// Round 2
// 1323.170 us; speedup vs baseline: 2.6670x; 2.6670x over previous
//
#include <hip/hip_runtime.h>
#include <hip/hip_bf16.h>
#include <math.h>

// ---------------- constants ----------------
#define BB 16
#define CC 192
#define SHIFT 8
#define NH 6
#define DD 32
#define NN 256       // tokens per window
#define HID 768
#define NWIN 256     // B * 16 windows
#define NROWS 65536  // B * H * W tokens

// ws byte offsets
#define OFF_TBL   0ll
#define OFF_BIAS  (64ll<<10)
#define OFF_W1B   (2ll<<20)
#define OFF_W2B   ((2ll<<20) + (512ll<<10))
#define OFF_Q     (4ll<<20)
#define OFF_K     (30ll<<20)
#define OFF_V     (56ll<<20)
#define OFF_AO    (82ll<<20)
#define OFF_HB    (4ll<<20)    // aliases Q (dead after attn)
#define OFF_H2    (30ll<<20)   // aliases K,V,AO (dead after proj) -> peak ~126MB
#define OFF_MLP   (4ll<<20)    // aliases HB (dead after fc1)

typedef __attribute__((ext_vector_type(4))) float f32x4;
typedef __attribute__((ext_vector_type(8))) short bf16x8;

__device__ __forceinline__ void gload16(const void* g, void* l) {
    __builtin_amdgcn_global_load_lds(
        (const __attribute__((address_space(1))) void*)g,
        (__attribute__((address_space(3))) void*)l, 16, 0, 0);
}

__device__ __forceinline__ float cpb_coord(int u) {
    float t = (float)u * (8.0f / 15.0f);
    return copysignf(log2f(fabsf(t) + 1.0f) * (1.0f / 3.0f), t);
}

// ---------------- CPB table MLP: tbl[m][h], m in [0,961) ----------------
__global__ __launch_bounds__(512) void k_tbl(
    const float* __restrict__ w1, const float* __restrict__ b1,
    const float* __restrict__ w2, float* __restrict__ tbl)
{
    __shared__ float r[512];
    int m = blockIdx.x;            // 0..960
    int a = m / 31, b = m % 31;
    float c0 = cpb_coord(a - 15);
    float c1 = cpb_coord(b - 15);
    int hd = threadIdx.x;          // 0..511
    float rv = c0 * w1[hd * 2 + 0] + c1 * w1[hd * 2 + 1] + b1[hd];
    r[hd] = fmaxf(rv, 0.0f);
    __syncthreads();
    if (hd < NH) {
        float s = 0.0f;
        for (int k = 0; k < 512; ++k) s += r[k] * w2[hd * 512 + k];
        tbl[m * NH + hd] = s;
    }
}

// ---------------- bias16[h][i][j] = 16*sigmoid(tbl[relidx(i,j)][h]) ----------------
__global__ __launch_bounds__(256) void k_bias(
    const float* __restrict__ tbl, float* __restrict__ bias16)
{
    int h = blockIdx.x >> 8;
    int i = blockIdx.x & 255;
    int j = threadIdx.x;
    int yi = i >> 4, xi = i & 15, yj = j >> 4, xj = j & 15;
    int idx = (yi - yj + 15) * 31 + (xi - xj + 15);
    float v = tbl[idx * NH + h];
    bias16[((size_t)h * NN + i) * NN + j] = 16.0f / (1.0f + __expf(-v));
}

// ---------------- weight fp32 -> bf16 ----------------
__global__ __launch_bounds__(256) void k_cvt(
    const float* __restrict__ w1, const float* __restrict__ w2,
    __hip_bfloat16* __restrict__ w1b, __hip_bfloat16* __restrict__ w2b)
{
    int i = blockIdx.x * 256 + threadIdx.x;
    const int NW = HID * CC;           // 147456
    if (i < NW) w1b[i] = __float2bfloat16(w1[i]);
    else { i -= NW; w2b[i] = __float2bfloat16(w2[i]); }
}

// ---------------- QKV: gather(roll+window) + 3 GEMMs + q/k norm ----------------
__global__ __launch_bounds__(256) void k_qkv(
    const float* __restrict__ x,
    const float* __restrict__ q_w, const float* __restrict__ q_b,
    const float* __restrict__ k_w,
    const float* __restrict__ v_w, const float* __restrict__ v_b,
    __hip_bfloat16* __restrict__ qn, __hip_bfloat16* __restrict__ kn,
    __hip_bfloat16* __restrict__ vv)
{
    __shared__ float xs[32][193];
    __shared__ float wt[32][193];
    __shared__ float out[32][193];
    __shared__ float rnorm[32][6];
    int tid = threadIdx.x;
    int rbase = blockIdx.x * 32;

    for (int idx = tid; idx < 32 * CC; idx += 256) {
        int t = idx / CC, c = idx % CC;
        int r = rbase + t;
        int win = r >> 8, n = r & 255;
        int b = win >> 4, wh = (win >> 2) & 3, ww = win & 3;
        int yi = n >> 4, xi = n & 15;
        int sy = (wh * 16 + yi + SHIFT) & 63;
        int sx = (ww * 16 + xi + SHIFT) & 63;
        xs[t][c] = x[((size_t)b * 4096 + sy * 64 + sx) * CC + c];
    }
    __syncthreads();

    for (int m = 0; m < 3; ++m) {
        const float* W  = (m == 0) ? q_w : (m == 1) ? k_w : v_w;
        const float* Bv = (m == 0) ? q_b : (m == 2) ? v_b : nullptr;
        for (int ocb = 0; ocb < CC; ocb += 32) {
            for (int idx = tid; idx < 32 * CC; idx += 256) {
                int o = idx / CC, c = idx % CC;
                wt[o][c] = W[(ocb + o) * CC + c];
            }
            __syncthreads();
            int tg = tid >> 4, og = tid & 15;
            int t0 = 2 * tg, t1 = t0 + 1, o0 = 2 * og, o1 = o0 + 1;
            float a00 = 0, a01 = 0, a10 = 0, a11 = 0;
            #pragma unroll 8
            for (int c = 0; c < CC; ++c) {
                float x0 = xs[t0][c], x1 = xs[t1][c];
                float w0 = wt[o0][c], w1 = wt[o1][c];
                a00 += x0 * w0; a01 += x0 * w1; a10 += x1 * w0; a11 += x1 * w1;
            }
            float bb0 = Bv ? Bv[ocb + o0] : 0.0f;
            float bb1 = Bv ? Bv[ocb + o1] : 0.0f;
            out[t0][ocb + o0] = a00 + bb0; out[t0][ocb + o1] = a01 + bb1;
            out[t1][ocb + o0] = a10 + bb0; out[t1][ocb + o1] = a11 + bb1;
            __syncthreads();
        }
        if (m < 2) {
            if (tid < 32 * NH) {
                int t = tid / NH, h = tid % NH;
                float s = 0.0f;
                #pragma unroll
                for (int d = 0; d < DD; ++d) { float v = out[t][h * DD + d]; s += v * v; }
                rnorm[t][h] = rsqrtf(s);
            }
        }
        __syncthreads();
        __hip_bfloat16* dst = (m == 0) ? qn : (m == 1) ? kn : vv;
        for (int idx = tid; idx < 32 * CC; idx += 256) {
            int t = idx / CC, c = idx % CC;
            int h = c >> 5, d = c & 31;
            float v = out[t][c];
            if (m < 2) v *= rnorm[t][h];
            int r = rbase + t;
            int win = r >> 8, n = r & 255;
            dst[(((size_t)win * NH + h) * NN + n) * DD + d] = __float2bfloat16(v);
        }
        __syncthreads();
    }
}

// ---------------- attention: one block per (window, head), flash-style ----------------
__global__ __launch_bounds__(256) void k_attn(
    const __hip_bfloat16* __restrict__ qn,
    const __hip_bfloat16* __restrict__ kn,
    const __hip_bfloat16* __restrict__ vv,
    const float* __restrict__ bias16,
    const float* __restrict__ logit_scale,
    __hip_bfloat16* __restrict__ ao)
{
    int wh_ = blockIdx.x;
    int win = wh_ / NH, h = wh_ % NH;
    int wwh = (win >> 2) & 3, www = win & 3;
    int i = threadIdx.x;                       // q row
    float scale = __expf(fminf(logit_scale[h], 4.6051702f));

    float q[DD];
    const __hip_bfloat16* qp = qn + (((size_t)win * NH + h) * NN + i) * DD;
    #pragma unroll
    for (int d = 0; d < DD; ++d) q[d] = __bfloat162float(qp[d]);

    int yi = i >> 4, xi = i & 15;
    int rhi = (wwh < 3) ? 0 : ((yi < SHIFT) ? 1 : 2);
    int rwi = (www < 3) ? 0 : ((xi < SHIFT) ? 1 : 2);
    int cnti = rhi * 3 + rwi;
    bool masked_win = (wwh == 3) || (www == 3);

    __shared__ float ks[32][33];
    __shared__ float vs[32][33];
    __shared__ float bs[256][33];

    float m = -1e30f, l = 0.0f;
    float acc[DD];
    #pragma unroll
    for (int d = 0; d < DD; ++d) acc[d] = 0.0f;

    const __hip_bfloat16* kbase = kn + (((size_t)win * NH + h) * NN) * DD;
    const __hip_bfloat16* vbase = vv + (((size_t)win * NH + h) * NN) * DD;
    const float* bbase = bias16 + ((size_t)h * NN + i) * NN;

    for (int jc = 0; jc < NN; jc += 32) {
        __syncthreads();
        for (int idx = i; idx < 32 * DD; idx += 256) {
            int jj = idx >> 5, d = idx & 31;
            ks[jj][d] = __bfloat162float(kbase[(jc + jj) * DD + d]);
            vs[jj][d] = __bfloat162float(vbase[(jc + jj) * DD + d]);
        }
        #pragma unroll
        for (int jj = 0; jj < 32; ++jj) bs[i][jj] = bbase[jc + jj];
        __syncthreads();
        for (int jj = 0; jj < 32; ++jj) {
            int j = jc + jj;
            float s = 0.0f;
            #pragma unroll
            for (int d = 0; d < DD; ++d) s += q[d] * ks[jj][d];
            s = s * scale + bs[i][jj];
            if (masked_win) {
                int yj = j >> 4, xj = j & 15;
                int rhj = (wwh < 3) ? 0 : ((yj < SHIFT) ? 1 : 2);
                int rwj = (www < 3) ? 0 : ((xj < SHIFT) ? 1 : 2);
                if (cnti != rhj * 3 + rwj) s -= 100.0f;
            }
            float mn = fmaxf(m, s);
            float corr = __expf(m - mn);
            float p = __expf(s - mn);
            l = l * corr + p;
            #pragma unroll
            for (int d = 0; d < DD; ++d) acc[d] = acc[d] * corr + p * vs[jj][d];
            m = mn;
        }
    }
    float rl = 1.0f / l;
    __hip_bfloat16* aop = ao + ((size_t)win * NN + i) * CC + h * DD;
    #pragma unroll
    for (int d = 0; d < DD; ++d) aop[d] = __float2bfloat16(acc[d] * rl);
}

// ---------------- proj + window-reverse + unroll + cond-LN1 residual ----------------
__global__ __launch_bounds__(256) void k_proj(
    const __hip_bfloat16* __restrict__ ao,
    const float* __restrict__ proj_w, const float* __restrict__ proj_b,
    const float* __restrict__ x, const float* __restrict__ time,
    const float* __restrict__ ww, const float* __restrict__ wb,
    const float* __restrict__ bw, const float* __restrict__ bb,
    float* __restrict__ hout, __hip_bfloat16* __restrict__ hb)
{
    __shared__ float xs[32][193];
    __shared__ float wt[32][193];
    __shared__ float out[32][193];
    __shared__ float mv[32][2];
    int tid = threadIdx.x;
    int rbase = blockIdx.x * 32;

    for (int idx = tid; idx < 32 * CC; idx += 256) {
        int t = idx / CC, c = idx % CC;
        int r = rbase + t;
        int b = r >> 12, p = r & 4095;
        int y = p >> 6, xc = p & 63;
        int gy = (y + 64 - SHIFT) & 63, gx = (xc + 64 - SHIFT) & 63;
        int win = (b << 4) + ((gy >> 4) << 2) + (gx >> 4);
        int n = ((gy & 15) << 4) + (gx & 15);
        xs[t][c] = __bfloat162float(ao[((size_t)win * NN + n) * CC + c]);
    }
    __syncthreads();
    for (int ocb = 0; ocb < CC; ocb += 32) {
        for (int idx = tid; idx < 32 * CC; idx += 256) {
            int o = idx / CC, c = idx % CC;
            wt[o][c] = proj_w[(ocb + o) * CC + c];
        }
        __syncthreads();
        int tg = tid >> 4, og = tid & 15;
        int t0 = 2 * tg, t1 = t0 + 1, o0 = 2 * og, o1 = o0 + 1;
        float a00 = 0, a01 = 0, a10 = 0, a11 = 0;
        #pragma unroll 8
        for (int c = 0; c < CC; ++c) {
            float x0 = xs[t0][c], x1 = xs[t1][c];
            float w0 = wt[o0][c], w1 = wt[o1][c];
            a00 += x0 * w0; a01 += x0 * w1; a10 += x1 * w0; a11 += x1 * w1;
        }
        out[t0][ocb + o0] = a00 + proj_b[ocb + o0];
        out[t0][ocb + o1] = a01 + proj_b[ocb + o1];
        out[t1][ocb + o0] = a10 + proj_b[ocb + o0];
        out[t1][ocb + o1] = a11 + proj_b[ocb + o1];
        __syncthreads();
    }
    if (tid < 32) {
        float s = 0, s2 = 0;
        for (int c = 0; c < CC; ++c) { float v = out[tid][c]; s += v; s2 += v * v; }
        float mean = s / (float)CC, var = s2 / (float)CC - mean * mean;
        mv[tid][0] = mean; mv[tid][1] = rsqrtf(var + 1e-5f);
    }
    __syncthreads();
    for (int idx = tid; idx < 32 * CC; idx += 256) {
        int t = idx / CC, c = idx % CC;
        int r = rbase + t;
        float tm = time[r >> 12];
        float w_ = tm * ww[c] + wb[c];
        float b_ = tm * bw[c] + bb[c];
        float xn = (out[t][c] - mv[t][0]) * mv[t][1];
        float hv = x[(size_t)r * CC + c] + w_ * xn + b_;
        hout[(size_t)r * CC + c] = hv;
        hb[(size_t)r * CC + c] = __float2bfloat16(hv);
    }
}

// ---------------- MFMA GEMM: C[M x N] = A[M x K] * W[N x K]^T (+bias, opt GELU) ----------------
// BM=128 fixed, BK=64, 4 waves as 2x2, wave tile 64 x (BN/2). EPI: 1=gelu, 2=plain.
template<int BN, int NWF, int EPI>
__global__ __launch_bounds__(256) void k_gemm(
    const __hip_bfloat16* __restrict__ A, const __hip_bfloat16* __restrict__ Bw,
    const float* __restrict__ bias, __hip_bfloat16* __restrict__ Cout,
    int K, int ldc)
{
    __shared__ short As[128 * 64];
    __shared__ short Bs[BN * 64];
    int tid = threadIdx.x;
    int lane = tid & 63;
    int w = tid >> 6, wr = w >> 1, wc = w & 1;
    int bm = blockIdx.x, bn = blockIdx.y;

    f32x4 acc[4][NWF];
    #pragma unroll
    for (int fm = 0; fm < 4; ++fm)
        #pragma unroll
        for (int fn = 0; fn < NWF; ++fn)
            acc[fm][fn] = (f32x4)0.0f;

    const int AR = (128 * 64) / (256 * 8);   // 4 staging rounds for A
    const int BR = (BN * 64) / (256 * 8);    // 4 or 2 for B

    for (int kt = 0; kt < K; kt += 64) {
        #pragma unroll
        for (int r = 0; r < AR; ++r) {
            int off = r * 256 + tid;
            int row = off >> 3, ce = (off & 7) * 8;
            gload16(A + ((size_t)(bm * 128 + row) * K + kt + ce), &As[off * 8]);
        }
        #pragma unroll
        for (int r = 0; r < BR; ++r) {
            int off = r * 256 + tid;
            int row = off >> 3, ce = (off & 7) * 8;
            gload16(Bw + ((size_t)(bn * BN + row) * K + kt + ce), &Bs[off * 8]);
        }
        __syncthreads();
        #pragma unroll
        for (int kk = 0; kk < 2; ++kk) {
            int kc = kk * 32 + (lane >> 4) * 8;
            bf16x8 af[4], bfr[NWF];
            #pragma unroll
            for (int fm = 0; fm < 4; ++fm)
                af[fm] = *(const bf16x8*)&As[(wr * 64 + fm * 16 + (lane & 15)) * 64 + kc];
            #pragma unroll
            for (int fn = 0; fn < NWF; ++fn)
                bfr[fn] = *(const bf16x8*)&Bs[(wc * (BN / 2) + fn * 16 + (lane & 15)) * 64 + kc];
            #pragma unroll
            for (int fm = 0; fm < 4; ++fm)
                #pragma unroll
                for (int fn = 0; fn < NWF; ++fn)
                    acc[fm][fn] = __builtin_amdgcn_mfma_f32_16x16x32_bf16(
                        af[fm], bfr[fn], acc[fm][fn], 0, 0, 0);
        }
        __syncthreads();
    }

    #pragma unroll
    for (int fm = 0; fm < 4; ++fm)
        #pragma unroll
        for (int fn = 0; fn < NWF; ++fn)
            #pragma unroll
            for (int r = 0; r < 4; ++r) {
                int rowg = bm * 128 + wr * 64 + fm * 16 + ((lane >> 4) << 2) + r;
                int colg = bn * BN + wc * (BN / 2) + fn * 16 + (lane & 15);
                float v = acc[fm][fn][r] + bias[colg];
                if (EPI == 1) v = 0.5f * v * (1.0f + erff(v * 0.70710678f));
                Cout[(size_t)rowg * ldc + colg] = __float2bfloat16(v);
            }
}

// ---------------- cond-LN2 + residual, in-place on d_out (one wave per row) ----------------
__global__ __launch_bounds__(256) void k_ln2(
    const __hip_bfloat16* __restrict__ mlpb,
    float* __restrict__ hio, const float* __restrict__ time,
    const float* __restrict__ ww, const float* __restrict__ wb,
    const float* __restrict__ bw, const float* __restrict__ bb)
{
    int row = blockIdx.x * 4 + (threadIdx.x >> 6);
    int lane = threadIdx.x & 63;
    float v[3];
    float s = 0.0f, s2 = 0.0f;
    #pragma unroll
    for (int j = 0; j < 3; ++j) {
        v[j] = __bfloat162float(mlpb[(size_t)row * CC + lane + j * 64]);
        s += v[j]; s2 += v[j] * v[j];
    }
    #pragma unroll
    for (int m = 1; m < 64; m <<= 1) {
        s  += __shfl_xor(s, m, 64);
        s2 += __shfl_xor(s2, m, 64);
    }
    float mean = s * (1.0f / (float)CC);
    float rstd = rsqrtf(s2 * (1.0f / (float)CC) - mean * mean + 1e-5f);
    float tm = time[row >> 12];
    #pragma unroll
    for (int j = 0; j < 3; ++j) {
        int c = lane + j * 64;
        float w_ = tm * ww[c] + wb[c];
        float b_ = tm * bw[c] + bb[c];
        size_t o = (size_t)row * CC + c;
        hio[o] = hio[o] + w_ * ((v[j] - mean) * rstd) + b_;
    }
}

extern "C" void kernel_launch(void* const* d_in, const int* in_sizes, int n_in,
                              void* d_out, int out_size, void* d_ws, size_t ws_size,
                              hipStream_t stream)
{
    const float* x        = (const float*)d_in[0];
    const float* time     = (const float*)d_in[1];
    const float* q_w      = (const float*)d_in[2];
    const float* q_b      = (const float*)d_in[3];
    const float* k_w      = (const float*)d_in[4];
    const float* v_w      = (const float*)d_in[5];
    const float* v_b      = (const float*)d_in[6];
    const float* lscale   = (const float*)d_in[7];
    const float* cpb_w1   = (const float*)d_in[8];
    const float* cpb_b1   = (const float*)d_in[9];
    const float* cpb_w2   = (const float*)d_in[10];
    const float* proj_w   = (const float*)d_in[11];
    const float* proj_b   = (const float*)d_in[12];
    const float* ln1_ww   = (const float*)d_in[13];
    const float* ln1_wb   = (const float*)d_in[14];
    const float* ln1_bw   = (const float*)d_in[15];
    const float* ln1_bb   = (const float*)d_in[16];
    const float* fc1_w    = (const float*)d_in[17];
    const float* fc1_b    = (const float*)d_in[18];
    const float* fc2_w    = (const float*)d_in[19];
    const float* fc2_b    = (const float*)d_in[20];
    const float* ln2_ww   = (const float*)d_in[21];
    const float* ln2_wb   = (const float*)d_in[22];
    const float* ln2_bw   = (const float*)d_in[23];
    const float* ln2_bb   = (const float*)d_in[24];

    char* ws = (char*)d_ws;
    float* tbl            = (float*)(ws + OFF_TBL);
    float* bias16         = (float*)(ws + OFF_BIAS);
    __hip_bfloat16* w1b   = (__hip_bfloat16*)(ws + OFF_W1B);
    __hip_bfloat16* w2b   = (__hip_bfloat16*)(ws + OFF_W2B);
    __hip_bfloat16* qn    = (__hip_bfloat16*)(ws + OFF_Q);
    __hip_bfloat16* kn    = (__hip_bfloat16*)(ws + OFF_K);
    __hip_bfloat16* vv    = (__hip_bfloat16*)(ws + OFF_V);
    __hip_bfloat16* ao    = (__hip_bfloat16*)(ws + OFF_AO);
    __hip_bfloat16* hb    = (__hip_bfloat16*)(ws + OFF_HB);
    __hip_bfloat16* h2    = (__hip_bfloat16*)(ws + OFF_H2);
    __hip_bfloat16* mlpb  = (__hip_bfloat16*)(ws + OFF_MLP);
    float* out            = (float*)d_out;

    k_tbl <<<961, 512, 0, stream>>>(cpb_w1, cpb_b1, cpb_w2, tbl);
    k_bias<<<NH * NN, 256, 0, stream>>>(tbl, bias16);
    k_cvt <<<(2 * HID * CC + 255) / 256, 256, 0, stream>>>(fc1_w, fc2_w, w1b, w2b);
    k_qkv <<<(NWIN * NN) / 32, 256, 0, stream>>>(x, q_w, q_b, k_w, v_w, v_b, qn, kn, vv);
    k_attn<<<NWIN * NH, 256, 0, stream>>>(qn, kn, vv, bias16, lscale, ao);
    k_proj<<<(NROWS) / 32, 256, 0, stream>>>(ao, proj_w, proj_b, x, time,
                                             ln1_ww, ln1_wb, ln1_bw, ln1_bb, out, hb);
    // fc1: M=65536, N=768, K=192 -> gelu -> h2 (bf16)
    k_gemm<128, 4, 1><<<dim3(NROWS / 128, HID / 128), 256, 0, stream>>>(
        hb, w1b, fc1_b, h2, CC, HID);
    // fc2: M=65536, N=192, K=768 -> mlpb (bf16, bias included)
    k_gemm<64, 2, 2><<<dim3(NROWS / 128, CC / 64), 256, 0, stream>>>(
        h2, w2b, fc2_b, mlpb, HID, CC);
    k_ln2 <<<NROWS / 4, 256, 0, stream>>>(mlpb, out, time,
                                          ln2_ww, ln2_wb, ln2_bw, ln2_bb);
}

// Round 3
// 648.229 us; speedup vs baseline: 5.4440x; 2.0412x over previous
//
#include <hip/hip_runtime.h>
#include <hip/hip_bf16.h>
#include <math.h>

// ---------------- constants ----------------
#define BB 16
#define CC 192
#define SHIFT 8
#define NH 6
#define DD 32
#define NN 256       // tokens per window
#define HID 768
#define NWIN 256     // B * 16 windows
#define NROWS 65536  // B * H * W tokens

// ws byte offsets
#define OFF_TBL   0ll
#define OFF_BIAS  (64ll<<10)
#define OFF_WQKV  (2ll<<20)
#define OFF_PWB   (2560ll<<10)
#define OFF_W1B   (3ll<<20)
#define OFF_W2B   (3584ll<<10)
#define OFF_BQKV  (3968ll<<10)
#define OFF_XB    (4ll<<20)
#define OFF_Q     (28ll<<20)
#define OFF_K     (52ll<<20)
#define OFF_V     (76ll<<20)
#define OFF_AO    (100ll<<20)
#define OFF_HB    (4ll<<20)    // aliases XB (dead after qkv gemm)
#define OFF_H2    (28ll<<20)   // aliases Q..AO (dead after projgemm)
#define OFF_MLP   (4ll<<20)    // aliases HB (dead after fc1)

typedef __attribute__((ext_vector_type(4))) float f32x4;
typedef __attribute__((ext_vector_type(8))) short bf16x8;

__device__ __forceinline__ void gload16(const void* g, void* l) {
    __builtin_amdgcn_global_load_lds(
        (const __attribute__((address_space(1))) void*)g,
        (__attribute__((address_space(3))) void*)l, 16, 0, 0);
}

__device__ __forceinline__ float b2f(short s) {
    unsigned u = ((unsigned)(unsigned short)s) << 16;
    return __builtin_bit_cast(float, u);
}
__device__ __forceinline__ short f2b(float f) {
    return __builtin_bit_cast(short, __float2bfloat16(f));
}

__device__ __forceinline__ float cpb_coord(int u) {
    float t = (float)u * (8.0f / 15.0f);
    return copysignf(log2f(fabsf(t) + 1.0f) * (1.0f / 3.0f), t);
}

// ---------------- CPB table MLP: tbl[m][h], m in [0,961) ----------------
__global__ __launch_bounds__(512) void k_tbl(
    const float* __restrict__ w1, const float* __restrict__ b1,
    const float* __restrict__ w2, float* __restrict__ tbl)
{
    __shared__ float r[512];
    int m = blockIdx.x;            // 0..960
    int a = m / 31, b = m % 31;
    float c0 = cpb_coord(a - 15);
    float c1 = cpb_coord(b - 15);
    int hd = threadIdx.x;          // 0..511
    float rv = c0 * w1[hd * 2 + 0] + c1 * w1[hd * 2 + 1] + b1[hd];
    r[hd] = fmaxf(rv, 0.0f);
    __syncthreads();
    if (hd < NH) {
        float s = 0.0f;
        for (int k = 0; k < 512; ++k) s += r[k] * w2[hd * 512 + k];
        tbl[m * NH + hd] = s;
    }
}

// ---------------- bias16[h][i][j] = 16*sigmoid(tbl[relidx(i,j)][h]) ----------------
__global__ __launch_bounds__(256) void k_bias(
    const float* __restrict__ tbl, float* __restrict__ bias16)
{
    int h = blockIdx.x >> 8;
    int i = blockIdx.x & 255;
    int j = threadIdx.x;
    int yi = i >> 4, xi = i & 15, yj = j >> 4, xj = j & 15;
    int idx = (yi - yj + 15) * 31 + (xi - xj + 15);
    float v = tbl[idx * NH + h];
    bias16[((size_t)h * NN + i) * NN + j] = 16.0f / (1.0f + __expf(-v));
}

// ---------------- weights fp32 -> bf16 (+ qkv bias concat) ----------------
__global__ __launch_bounds__(256) void k_cvt(
    const float* __restrict__ qw, const float* __restrict__ kw,
    const float* __restrict__ vw, const float* __restrict__ pw,
    const float* __restrict__ fc1w, const float* __restrict__ fc2w,
    const float* __restrict__ q_b, const float* __restrict__ v_b,
    __hip_bfloat16* __restrict__ wqkv, __hip_bfloat16* __restrict__ pwb,
    __hip_bfloat16* __restrict__ w1b, __hip_bfloat16* __restrict__ w2b,
    float* __restrict__ bqkv)
{
    int i = blockIdx.x * 256 + threadIdx.x;
    const int S1 = 36864, S2 = 73728, S3 = 110592, S4 = 147456,
              S5 = 294912, S6 = 442368, S7 = 442944;
    if (i < S3) {
        const float* src = (i < S1) ? qw : (i < S2) ? kw : vw;
        int off = (i < S1) ? i : (i < S2) ? i - S1 : i - S2;
        wqkv[i] = __float2bfloat16(src[off]);
    } else if (i < S4) { pwb[i - S3] = __float2bfloat16(pw[i - S3]); }
    else if (i < S5)   { w1b[i - S4] = __float2bfloat16(fc1w[i - S4]); }
    else if (i < S6)   { w2b[i - S5] = __float2bfloat16(fc2w[i - S5]); }
    else if (i < S7) {
        int j = i - S6;
        bqkv[j] = (j < 192) ? q_b[j] : (j < 384) ? 0.0f : v_b[j - 384];
    }
}

// ---------------- roll + window-partition gather: x fp32 -> xb bf16 [65536][192] ----------------
__global__ __launch_bounds__(256) void k_gather(
    const float* __restrict__ x, __hip_bfloat16* __restrict__ xb)
{
    int idx = blockIdx.x * 256 + threadIdx.x;   // one per 4 channels
    int r = idx / 48, c4 = idx % 48;
    int win = r >> 8, n = r & 255;
    int b = win >> 4, wh = (win >> 2) & 3, ww = win & 3;
    int yi = n >> 4, xi = n & 15;
    int sy = (wh * 16 + yi + SHIFT) & 63;
    int sx = (ww * 16 + xi + SHIFT) & 63;
    float4 v = *(const float4*)&x[((size_t)b * 4096 + sy * 64 + sx) * CC + c4 * 4];
    union { short h[4]; short4 s4; } u;
    u.h[0] = f2b(v.x); u.h[1] = f2b(v.y); u.h[2] = f2b(v.z); u.h[3] = f2b(v.w);
    *(short4*)&((short*)xb)[(size_t)r * CC + c4 * 4] = u.s4;
}

// ---------------- QKV MFMA GEMM: [65536x192] @ wqkv[576x192]^T, fused q/k head-norm ----------------
__global__ __launch_bounds__(256) void k_qkvgemm(
    const __hip_bfloat16* __restrict__ A, const __hip_bfloat16* __restrict__ Bw,
    const float* __restrict__ bias,
    __hip_bfloat16* __restrict__ qbo, __hip_bfloat16* __restrict__ kbo,
    __hip_bfloat16* __restrict__ vbo)
{
    __shared__ short As[128 * 64];
    __shared__ short Bs[64 * 64];
    int tid = threadIdx.x, lane = tid & 63;
    int w = tid >> 6, wr = w >> 1, wc = w & 1;
    int bm = blockIdx.x, bn = blockIdx.y;

    f32x4 acc[4][2];
    #pragma unroll
    for (int fm = 0; fm < 4; ++fm)
        #pragma unroll
        for (int fn = 0; fn < 2; ++fn) acc[fm][fn] = (f32x4)0.0f;

    for (int kt = 0; kt < CC; kt += 64) {
        #pragma unroll
        for (int r = 0; r < 4; ++r) {
            int off = r * 256 + tid;
            int row = off >> 3, ce = (off & 7) * 8;
            gload16(A + ((size_t)(bm * 128 + row) * CC + kt + ce), &As[off * 8]);
        }
        #pragma unroll
        for (int r = 0; r < 2; ++r) {
            int off = r * 256 + tid;
            int row = off >> 3, ce = (off & 7) * 8;
            gload16(Bw + ((size_t)(bn * 64 + row) * CC + kt + ce), &Bs[off * 8]);
        }
        __syncthreads();
        #pragma unroll
        for (int kk = 0; kk < 2; ++kk) {
            int kc = kk * 32 + (lane >> 4) * 8;
            bf16x8 af[4], bfr[2];
            #pragma unroll
            for (int fm = 0; fm < 4; ++fm)
                af[fm] = *(const bf16x8*)&As[(wr * 64 + fm * 16 + (lane & 15)) * 64 + kc];
            #pragma unroll
            for (int fn = 0; fn < 2; ++fn)
                bfr[fn] = *(const bf16x8*)&Bs[(wc * 32 + fn * 16 + (lane & 15)) * 64 + kc];
            #pragma unroll
            for (int fm = 0; fm < 4; ++fm)
                #pragma unroll
                for (int fn = 0; fn < 2; ++fn)
                    acc[fm][fn] = __builtin_amdgcn_mfma_f32_16x16x32_bf16(
                        af[fm], bfr[fn], acc[fm][fn], 0, 0, 0);
        }
        __syncthreads();
    }

    __hip_bfloat16* dst = (bn < 3) ? qbo : (bn < 6) ? kbo : vbo;
    int cbase = (bn % 3) * 64 + wc * 32;
    bool donorm = (bn < 6);
    int bcol = bn * 64 + wc * 32 + (lane & 15);
    #pragma unroll
    for (int fm = 0; fm < 4; ++fm)
        #pragma unroll
        for (int r = 0; r < 4; ++r) {
            float v0 = acc[fm][0][r] + bias[bcol];
            float v1 = acc[fm][1][r] + bias[bcol + 16];
            if (donorm) {
                float s2 = v0 * v0 + v1 * v1;
                s2 += __shfl_xor(s2, 1);
                s2 += __shfl_xor(s2, 2);
                s2 += __shfl_xor(s2, 4);
                s2 += __shfl_xor(s2, 8);
                float rn = rsqrtf(s2);
                v0 *= rn; v1 *= rn;
            }
            int rowg = bm * 128 + wr * 64 + fm * 16 + ((lane >> 4) << 2) + r;
            dst[(size_t)rowg * CC + cbase + (lane & 15)] = __float2bfloat16(v0);
            dst[(size_t)rowg * CC + cbase + 16 + (lane & 15)] = __float2bfloat16(v1);
        }
}

// ---------------- attention: one block per (window, head), static-max softmax ----------------
__global__ __launch_bounds__(256) void k_attn(
    const __hip_bfloat16* __restrict__ qb,
    const __hip_bfloat16* __restrict__ kb,
    const __hip_bfloat16* __restrict__ vb,
    const float* __restrict__ bias16,
    const float* __restrict__ logit_scale,
    __hip_bfloat16* __restrict__ ao)
{
    __shared__ float ks[32][33];
    __shared__ float vs[32][33];
    __shared__ float bs[256][33];
    int wh_ = blockIdx.x;
    int win = wh_ / NH, h = wh_ % NH;
    int wwh = (win >> 2) & 3, www = win & 3;
    int i = threadIdx.x;                       // q row
    float scale = __expf(fminf(logit_scale[h], 4.6051702f));
    float M = scale + 16.0f;                   // static bound: |cos|<=1 * scale + bias<16

    float q[DD];
    const __hip_bfloat16* qp = qb + ((size_t)(win * NN + i)) * CC + h * DD;
    #pragma unroll
    for (int jv = 0; jv < 4; ++jv) {
        bf16x8 t = *(const bf16x8*)(qp + jv * 8);
        #pragma unroll
        for (int e = 0; e < 8; ++e) q[jv * 8 + e] = b2f(t[e]);
    }

    int yi = i >> 4, xi = i & 15;
    int rhi = (wwh < 3) ? 0 : ((yi < SHIFT) ? 1 : 2);
    int rwi = (www < 3) ? 0 : ((xi < SHIFT) ? 1 : 2);
    int cnti = rhi * 3 + rwi;
    bool masked_win = (wwh == 3) || (www == 3);

    float l = 0.0f;
    float acc[DD];
    #pragma unroll
    for (int d = 0; d < DD; ++d) acc[d] = 0.0f;

    const __hip_bfloat16* kbase = kb + (size_t)win * NN * CC + h * DD;
    const __hip_bfloat16* vbase = vb + (size_t)win * NN * CC + h * DD;
    const float* bbase = bias16 + ((size_t)h * NN + i) * NN;

    for (int jc = 0; jc < NN; jc += 32) {
        __syncthreads();
        {
            int sidx = i & 127;
            int jj = sidx >> 2, d8 = (sidx & 3) * 8;
            const __hip_bfloat16* src = (i < 128) ? kbase : vbase;
            bf16x8 t = *(const bf16x8*)(src + (size_t)(jc + jj) * CC + d8);
            float* drow = (i < 128) ? ks[jj] : vs[jj];
            #pragma unroll
            for (int e = 0; e < 8; ++e) drow[d8 + e] = b2f(t[e]);
        }
        #pragma unroll
        for (int j4 = 0; j4 < 8; ++j4) {
            float4 bv = *(const float4*)&bbase[jc + j4 * 4];
            bs[i][j4 * 4 + 0] = bv.x; bs[i][j4 * 4 + 1] = bv.y;
            bs[i][j4 * 4 + 2] = bv.z; bs[i][j4 * 4 + 3] = bv.w;
        }
        __syncthreads();
        #pragma unroll 4
        for (int jj = 0; jj < 32; ++jj) {
            int j = jc + jj;
            float s = 0.0f;
            #pragma unroll
            for (int d = 0; d < DD; ++d) s += q[d] * ks[jj][d];
            s = s * scale + bs[i][jj];
            if (masked_win) {
                int yj = j >> 4, xj = j & 15;
                int rhj = (wwh < 3) ? 0 : ((yj < SHIFT) ? 1 : 2);
                int rwj = (www < 3) ? 0 : ((xj < SHIFT) ? 1 : 2);
                if (cnti != rhj * 3 + rwj) s -= 100.0f;
            }
            float p = __expf(s - M);
            l += p;
            #pragma unroll
            for (int d = 0; d < DD; ++d) acc[d] += p * vs[jj][d];
        }
    }
    float rl = 1.0f / l;
    __hip_bfloat16* aop = ao + ((size_t)(win * NN + i)) * CC + h * DD;
    #pragma unroll
    for (int jv = 0; jv < 4; ++jv) {
        bf16x8 o;
        #pragma unroll
        for (int e = 0; e < 8; ++e) o[e] = f2b(acc[jv * 8 + e] * rl);
        *(bf16x8*)(aop + jv * 8) = o;
    }
}

// ---------------- proj MFMA GEMM + window-reverse + cond-LN1 + residual ----------------
__global__ __launch_bounds__(256) void k_projgemm(
    const __hip_bfloat16* __restrict__ ao,
    const __hip_bfloat16* __restrict__ pwb,
    const float* __restrict__ pbias,
    const float* __restrict__ x, const float* __restrict__ time,
    const float* __restrict__ ww, const float* __restrict__ wb,
    const float* __restrict__ bw, const float* __restrict__ bb,
    float* __restrict__ hout, __hip_bfloat16* __restrict__ hb)
{
    __shared__ short As[128 * 64];
    __shared__ short Bs[192 * 64];
    __shared__ float part[128][4];
    int tid = threadIdx.x, lane = tid & 63;
    int w = tid >> 6, wr = w >> 1, wc = w & 1;
    int bm = blockIdx.x;

    f32x4 acc[4][6];
    #pragma unroll
    for (int fm = 0; fm < 4; ++fm)
        #pragma unroll
        for (int fn = 0; fn < 6; ++fn) acc[fm][fn] = (f32x4)0.0f;

    for (int kt = 0; kt < CC; kt += 64) {
        #pragma unroll
        for (int r = 0; r < 4; ++r) {
            int off = r * 256 + tid;
            int row = off >> 3, ce = (off & 7) * 8;
            gload16(ao + ((size_t)(bm * 128 + row) * CC + kt + ce), &As[off * 8]);
        }
        #pragma unroll
        for (int r = 0; r < 6; ++r) {
            int off = r * 256 + tid;
            int row = off >> 3, ce = (off & 7) * 8;
            gload16(pwb + ((size_t)row * CC + kt + ce), &Bs[off * 8]);
        }
        __syncthreads();
        #pragma unroll
        for (int kk = 0; kk < 2; ++kk) {
            int kc = kk * 32 + (lane >> 4) * 8;
            bf16x8 af[4], bfr[6];
            #pragma unroll
            for (int fm = 0; fm < 4; ++fm)
                af[fm] = *(const bf16x8*)&As[(wr * 64 + fm * 16 + (lane & 15)) * 64 + kc];
            #pragma unroll
            for (int fn = 0; fn < 6; ++fn)
                bfr[fn] = *(const bf16x8*)&Bs[(wc * 96 + fn * 16 + (lane & 15)) * 64 + kc];
            #pragma unroll
            for (int fm = 0; fm < 4; ++fm)
                #pragma unroll
                for (int fn = 0; fn < 6; ++fn)
                    acc[fm][fn] = __builtin_amdgcn_mfma_f32_16x16x32_bf16(
                        af[fm], bfr[fn], acc[fm][fn], 0, 0, 0);
        }
        __syncthreads();
    }

    // bias add + per-row LN partials (each wave owns 96 of 192 cols)
    #pragma unroll
    for (int fm = 0; fm < 4; ++fm)
        #pragma unroll
        for (int r = 0; r < 4; ++r) {
            float s = 0.0f, s2 = 0.0f;
            #pragma unroll
            for (int fn = 0; fn < 6; ++fn) {
                int col = wc * 96 + fn * 16 + (lane & 15);
                float v = acc[fm][fn][r] + pbias[col];
                acc[fm][fn][r] = v;
                s += v; s2 += v * v;
            }
            #pragma unroll
            for (int m = 1; m < 16; m <<= 1) {
                s  += __shfl_xor(s, m);
                s2 += __shfl_xor(s2, m);
            }
            if ((lane & 15) == 0) {
                int rl = wr * 64 + fm * 16 + ((lane >> 4) << 2) + r;
                part[rl][wc * 2]     = s;
                part[rl][wc * 2 + 1] = s2;
            }
        }
    __syncthreads();

    int win = bm >> 1;                 // 128 rows = half a window -> uniform
    int b = win >> 4, wh = (win >> 2) & 3, wwn = win & 3;
    float tm = time[b];
    #pragma unroll
    for (int fm = 0; fm < 4; ++fm)
        #pragma unroll
        for (int r = 0; r < 4; ++r) {
            int rl = wr * 64 + fm * 16 + ((lane >> 4) << 2) + r;
            float s  = part[rl][0] + part[rl][2];
            float s2 = part[rl][1] + part[rl][3];
            float mean = s * (1.0f / 192.0f);
            float rstd = rsqrtf(s2 * (1.0f / 192.0f) - mean * mean + 1e-5f);
            int rw = bm * 128 + rl;
            int n = rw & 255;
            int yi = n >> 4, xi = n & 15;
            int y  = (wh * 16 + yi + SHIFT) & 63;
            int xq = (wwn * 16 + xi + SHIFT) & 63;
            size_t rimg = (size_t)b * 4096 + y * 64 + xq;
            #pragma unroll
            for (int fn = 0; fn < 6; ++fn) {
                int col = wc * 96 + fn * 16 + (lane & 15);
                float w_ = tm * ww[col] + wb[col];
                float b_ = tm * bw[col] + bb[col];
                float xn = (acc[fm][fn][r] - mean) * rstd;
                float hv = x[rimg * CC + col] + w_ * xn + b_;
                hout[rimg * CC + col] = hv;
                hb[rimg * CC + col] = __float2bfloat16(hv);
            }
        }
}

// ---------------- MFMA GEMM: C[M x N] = A[M x K] * W[N x K]^T (+bias, opt GELU) ----------------
template<int BN, int NWF, int EPI>
__global__ __launch_bounds__(256) void k_gemm(
    const __hip_bfloat16* __restrict__ A, const __hip_bfloat16* __restrict__ Bw,
    const float* __restrict__ bias, __hip_bfloat16* __restrict__ Cout,
    int K, int ldc)
{
    __shared__ short As[128 * 64];
    __shared__ short Bs[BN * 64];
    int tid = threadIdx.x;
    int lane = tid & 63;
    int w = tid >> 6, wr = w >> 1, wc = w & 1;
    int bm = blockIdx.x, bn = blockIdx.y;

    f32x4 acc[4][NWF];
    #pragma unroll
    for (int fm = 0; fm < 4; ++fm)
        #pragma unroll
        for (int fn = 0; fn < NWF; ++fn)
            acc[fm][fn] = (f32x4)0.0f;

    const int AR = (128 * 64) / (256 * 8);
    const int BR = (BN * 64) / (256 * 8);

    for (int kt = 0; kt < K; kt += 64) {
        #pragma unroll
        for (int r = 0; r < AR; ++r) {
            int off = r * 256 + tid;
            int row = off >> 3, ce = (off & 7) * 8;
            gload16(A + ((size_t)(bm * 128 + row) * K + kt + ce), &As[off * 8]);
        }
        #pragma unroll
        for (int r = 0; r < BR; ++r) {
            int off = r * 256 + tid;
            int row = off >> 3, ce = (off & 7) * 8;
            gload16(Bw + ((size_t)(bn * BN + row) * K + kt + ce), &Bs[off * 8]);
        }
        __syncthreads();
        #pragma unroll
        for (int kk = 0; kk < 2; ++kk) {
            int kc = kk * 32 + (lane >> 4) * 8;
            bf16x8 af[4], bfr[NWF];
            #pragma unroll
            for (int fm = 0; fm < 4; ++fm)
                af[fm] = *(const bf16x8*)&As[(wr * 64 + fm * 16 + (lane & 15)) * 64 + kc];
            #pragma unroll
            for (int fn = 0; fn < NWF; ++fn)
                bfr[fn] = *(const bf16x8*)&Bs[(wc * (BN / 2) + fn * 16 + (lane & 15)) * 64 + kc];
            #pragma unroll
            for (int fm = 0; fm < 4; ++fm)
                #pragma unroll
                for (int fn = 0; fn < NWF; ++fn)
                    acc[fm][fn] = __builtin_amdgcn_mfma_f32_16x16x32_bf16(
                        af[fm], bfr[fn], acc[fm][fn], 0, 0, 0);
        }
        __syncthreads();
    }

    #pragma unroll
    for (int fm = 0; fm < 4; ++fm)
        #pragma unroll
        for (int fn = 0; fn < NWF; ++fn)
            #pragma unroll
            for (int r = 0; r < 4; ++r) {
                int rowg = bm * 128 + wr * 64 + fm * 16 + ((lane >> 4) << 2) + r;
                int colg = bn * BN + wc * (BN / 2) + fn * 16 + (lane & 15);
                float v = acc[fm][fn][r] + bias[colg];
                if (EPI == 1) v = 0.5f * v * (1.0f + erff(v * 0.70710678f));
                Cout[(size_t)rowg * ldc + colg] = __float2bfloat16(v);
            }
}

// ---------------- cond-LN2 + residual, in-place on d_out (one wave per row) ----------------
__global__ __launch_bounds__(256) void k_ln2(
    const __hip_bfloat16* __restrict__ mlpb,
    float* __restrict__ hio, const float* __restrict__ time,
    const float* __restrict__ ww, const float* __restrict__ wb,
    const float* __restrict__ bw, const float* __restrict__ bb)
{
    int row = blockIdx.x * 4 + (threadIdx.x >> 6);
    int lane = threadIdx.x & 63;
    float v[3];
    float s = 0.0f, s2 = 0.0f;
    #pragma unroll
    for (int j = 0; j < 3; ++j) {
        v[j] = __bfloat162float(mlpb[(size_t)row * CC + lane + j * 64]);
        s += v[j]; s2 += v[j] * v[j];
    }
    #pragma unroll
    for (int m = 1; m < 64; m <<= 1) {
        s  += __shfl_xor(s, m, 64);
        s2 += __shfl_xor(s2, m, 64);
    }
    float mean = s * (1.0f / (float)CC);
    float rstd = rsqrtf(s2 * (1.0f / (float)CC) - mean * mean + 1e-5f);
    float tm = time[row >> 12];
    #pragma unroll
    for (int j = 0; j < 3; ++j) {
        int c = lane + j * 64;
        float w_ = tm * ww[c] + wb[c];
        float b_ = tm * bw[c] + bb[c];
        size_t o = (size_t)row * CC + c;
        hio[o] = hio[o] + w_ * ((v[j] - mean) * rstd) + b_;
    }
}

extern "C" void kernel_launch(void* const* d_in, const int* in_sizes, int n_in,
                              void* d_out, int out_size, void* d_ws, size_t ws_size,
                              hipStream_t stream)
{
    const float* x        = (const float*)d_in[0];
    const float* time     = (const float*)d_in[1];
    const float* q_w      = (const float*)d_in[2];
    const float* q_b      = (const float*)d_in[3];
    const float* k_w      = (const float*)d_in[4];
    const float* v_w      = (const float*)d_in[5];
    const float* v_b      = (const float*)d_in[6];
    const float* lscale   = (const float*)d_in[7];
    const float* cpb_w1   = (const float*)d_in[8];
    const float* cpb_b1   = (const float*)d_in[9];
    const float* cpb_w2   = (const float*)d_in[10];
    const float* proj_w   = (const float*)d_in[11];
    const float* proj_b   = (const float*)d_in[12];
    const float* ln1_ww   = (const float*)d_in[13];
    const float* ln1_wb   = (const float*)d_in[14];
    const float* ln1_bw   = (const float*)d_in[15];
    const float* ln1_bb   = (const float*)d_in[16];
    const float* fc1_w    = (const float*)d_in[17];
    const float* fc1_b    = (const float*)d_in[18];
    const float* fc2_w    = (const float*)d_in[19];
    const float* fc2_b    = (const float*)d_in[20];
    const float* ln2_ww   = (const float*)d_in[21];
    const float* ln2_wb   = (const float*)d_in[22];
    const float* ln2_bw   = (const float*)d_in[23];
    const float* ln2_bb   = (const float*)d_in[24];

    char* ws = (char*)d_ws;
    float* tbl            = (float*)(ws + OFF_TBL);
    float* bias16         = (float*)(ws + OFF_BIAS);
    __hip_bfloat16* wqkv  = (__hip_bfloat16*)(ws + OFF_WQKV);
    __hip_bfloat16* pwb   = (__hip_bfloat16*)(ws + OFF_PWB);
    __hip_bfloat16* w1b   = (__hip_bfloat16*)(ws + OFF_W1B);
    __hip_bfloat16* w2b   = (__hip_bfloat16*)(ws + OFF_W2B);
    float* bqkv           = (float*)(ws + OFF_BQKV);
    __hip_bfloat16* xb    = (__hip_bfloat16*)(ws + OFF_XB);
    __hip_bfloat16* qb    = (__hip_bfloat16*)(ws + OFF_Q);
    __hip_bfloat16* kb    = (__hip_bfloat16*)(ws + OFF_K);
    __hip_bfloat16* vb    = (__hip_bfloat16*)(ws + OFF_V);
    __hip_bfloat16* ao    = (__hip_bfloat16*)(ws + OFF_AO);
    __hip_bfloat16* hb    = (__hip_bfloat16*)(ws + OFF_HB);
    __hip_bfloat16* h2    = (__hip_bfloat16*)(ws + OFF_H2);
    __hip_bfloat16* mlpb  = (__hip_bfloat16*)(ws + OFF_MLP);
    float* out            = (float*)d_out;

    k_tbl   <<<961, 512, 0, stream>>>(cpb_w1, cpb_b1, cpb_w2, tbl);
    k_bias  <<<NH * NN, 256, 0, stream>>>(tbl, bias16);
    k_cvt   <<<1731, 256, 0, stream>>>(q_w, k_w, v_w, proj_w, fc1_w, fc2_w,
                                       q_b, v_b, wqkv, pwb, w1b, w2b, bqkv);
    k_gather<<<12288, 256, 0, stream>>>(x, xb);
    k_qkvgemm<<<dim3(NROWS / 128, 9), 256, 0, stream>>>(xb, wqkv, bqkv, qb, kb, vb);
    k_attn  <<<NWIN * NH, 256, 0, stream>>>(qb, kb, vb, bias16, lscale, ao);
    k_projgemm<<<NROWS / 128, 256, 0, stream>>>(ao, pwb, proj_b, x, time,
                                                ln1_ww, ln1_wb, ln1_bw, ln1_bb, out, hb);
    k_gemm<128, 4, 1><<<dim3(NROWS / 128, HID / 128), 256, 0, stream>>>(
        hb, w1b, fc1_b, h2, CC, HID);
    k_gemm<64, 2, 2><<<dim3(NROWS / 128, CC / 64), 256, 0, stream>>>(
        h2, w2b, fc2_b, mlpb, HID, CC);
    k_ln2  <<<NROWS / 4, 256, 0, stream>>>(mlpb, out, time,
                                           ln2_ww, ln2_wb, ln2_bw, ln2_bb);
}

// Round 4
// 323.175 us; speedup vs baseline: 10.9196x; 2.0058x over previous
//
#include <hip/hip_runtime.h>
#include <hip/hip_bf16.h>
#include <math.h>

// ---------------- constants ----------------
#define BB 16
#define CC 192
#define SHIFT 8
#define NH 6
#define DD 32
#define NN 256       // tokens per window
#define HID 768
#define NWIN 256     // B * 16 windows
#define NROWS 65536  // B * H * W tokens

// ws byte offsets
#define OFF_TBL   0ll
#define OFF_BIASM (32ll<<10)      // 4*6*256*256*4 = 6,291,456
#define OFF_WQKV  (6208ll<<10)    // 221,184
#define OFF_PWB   (6424ll<<10)    // 73,728
#define OFF_W1B   (6496ll<<10)    // 294,912
#define OFF_W2B   (6784ll<<10)    // 294,912
#define OFF_BQKV  (7072ll<<10)    // 2,304
#define OFF_XB    (8ll<<20)       // 25,165,824 -> ends at 32MB
#define OFF_Q     (32ll<<20)
#define OFF_K     (56ll<<20)
#define OFF_V     (80ll<<20)
#define OFF_AO    (104ll<<20)     // ends 128MB
#define OFF_HB    OFF_XB          // aliases XB (dead after qkv gemm)
#define OFF_H2    OFF_Q           // aliases Q..AO (dead after projgemm); ends 128MB
#define OFF_MLP   OFF_XB          // aliases HB (dead after fc1)

typedef __attribute__((ext_vector_type(4)))  float f32x4;
typedef __attribute__((ext_vector_type(16))) float f32x16;
typedef __attribute__((ext_vector_type(8)))  short bf16x8;

__device__ __forceinline__ void gload16(const void* g, void* l) {
    __builtin_amdgcn_global_load_lds(
        (const __attribute__((address_space(1))) void*)g,
        (__attribute__((address_space(3))) void*)l, 16, 0, 0);
}

__device__ __forceinline__ short f2b(float f) {
    return __builtin_bit_cast(short, __float2bfloat16(f));
}
__device__ __forceinline__ unsigned pk2(float lo, float hi) {
    unsigned a = (unsigned short)f2b(lo);
    unsigned b = (unsigned short)f2b(hi);
    return a | (b << 16);
}

__device__ __forceinline__ float cpb_coord(int u) {
    float t = (float)u * (8.0f / 15.0f);
    return copysignf(log2f(fabsf(t) + 1.0f) * (1.0f / 3.0f), t);
}

// ---------------- CPB table MLP: tbl[m][h], m in [0,961) ----------------
__global__ __launch_bounds__(512) void k_tbl(
    const float* __restrict__ w1, const float* __restrict__ b1,
    const float* __restrict__ w2, float* __restrict__ tbl)
{
    __shared__ float r[512];
    int m = blockIdx.x;            // 0..960
    int a = m / 31, b = m % 31;
    float c0 = cpb_coord(a - 15);
    float c1 = cpb_coord(b - 15);
    int hd = threadIdx.x;          // 0..511
    float rv = c0 * w1[hd * 2 + 0] + c1 * w1[hd * 2 + 1] + b1[hd];
    r[hd] = fmaxf(rv, 0.0f);
    __syncthreads();
    if (hd < NH) {
        float s = 0.0f;
        for (int k = 0; k < 512; ++k) s += r[k] * w2[hd * 512 + k];
        tbl[m * NH + hd] = s;
    }
}

// ---------------- biasm[ty][h][i][j] = 16*sigmoid(rpb) + mask(ty) ----------------
__global__ __launch_bounds__(256) void k_biasm(
    const float* __restrict__ tbl, float* __restrict__ biasm)
{
    int bid = blockIdx.x;
    int ty = bid / (NH * NN);
    int rem = bid % (NH * NN);
    int h = rem >> 8, i = rem & 255;
    int j = threadIdx.x;
    int yi = i >> 4, xi = i & 15, yj = j >> 4, xj = j & 15;
    int idx = (yi - yj + 15) * 31 + (xi - xj + 15);
    float v = 16.0f / (1.0f + __expf(-tbl[idx * NH + h]));
    int rhi = (ty & 2) ? ((yi < SHIFT) ? 1 : 2) : 0;
    int rwi = (ty & 1) ? ((xi < SHIFT) ? 1 : 2) : 0;
    int rhj = (ty & 2) ? ((yj < SHIFT) ? 1 : 2) : 0;
    int rwj = (ty & 1) ? ((xj < SHIFT) ? 1 : 2) : 0;
    if (rhi * 3 + rwi != rhj * 3 + rwj) v -= 100.0f;
    biasm[(((size_t)ty * NH + h) * NN + i) * NN + j] = v;
}

// ---------------- weights fp32 -> bf16 (+ qkv bias concat) ----------------
__global__ __launch_bounds__(256) void k_cvt(
    const float* __restrict__ qw, const float* __restrict__ kw,
    const float* __restrict__ vw, const float* __restrict__ pw,
    const float* __restrict__ fc1w, const float* __restrict__ fc2w,
    const float* __restrict__ q_b, const float* __restrict__ v_b,
    __hip_bfloat16* __restrict__ wqkv, __hip_bfloat16* __restrict__ pwb,
    __hip_bfloat16* __restrict__ w1b, __hip_bfloat16* __restrict__ w2b,
    float* __restrict__ bqkv)
{
    int i = blockIdx.x * 256 + threadIdx.x;
    const int S1 = 36864, S2 = 73728, S3 = 110592, S4 = 147456,
              S5 = 294912, S6 = 442368, S7 = 442944;
    if (i < S3) {
        const float* src = (i < S1) ? qw : (i < S2) ? kw : vw;
        int off = (i < S1) ? i : (i < S2) ? i - S1 : i - S2;
        wqkv[i] = __float2bfloat16(src[off]);
    } else if (i < S4) { pwb[i - S3] = __float2bfloat16(pw[i - S3]); }
    else if (i < S5)   { w1b[i - S4] = __float2bfloat16(fc1w[i - S4]); }
    else if (i < S6)   { w2b[i - S5] = __float2bfloat16(fc2w[i - S5]); }
    else if (i < S7) {
        int j = i - S6;
        bqkv[j] = (j < 192) ? q_b[j] : (j < 384) ? 0.0f : v_b[j - 384];
    }
}

// ---------------- roll + window-partition gather: x fp32 -> xb bf16 [65536][192] ----------------
__global__ __launch_bounds__(256) void k_gather(
    const float* __restrict__ x, __hip_bfloat16* __restrict__ xb)
{
    int idx = blockIdx.x * 256 + threadIdx.x;   // one per 4 channels
    int r = idx / 48, c4 = idx % 48;
    int win = r >> 8, n = r & 255;
    int b = win >> 4, wh = (win >> 2) & 3, ww = win & 3;
    int yi = n >> 4, xi = n & 15;
    int sy = (wh * 16 + yi + SHIFT) & 63;
    int sx = (ww * 16 + xi + SHIFT) & 63;
    float4 v = *(const float4*)&x[((size_t)b * 4096 + sy * 64 + sx) * CC + c4 * 4];
    union { short h[4]; short4 s4; } u;
    u.h[0] = f2b(v.x); u.h[1] = f2b(v.y); u.h[2] = f2b(v.z); u.h[3] = f2b(v.w);
    *(short4*)&((short*)xb)[(size_t)r * CC + c4 * 4] = u.s4;
}

// ---------------- QKV MFMA GEMM + fused q/k head-norm (+scale folded into q) ----------------
__global__ __launch_bounds__(256) void k_qkvgemm(
    const __hip_bfloat16* __restrict__ A, const __hip_bfloat16* __restrict__ Bw,
    const float* __restrict__ bias, const float* __restrict__ lscale,
    __hip_bfloat16* __restrict__ qbo, __hip_bfloat16* __restrict__ kbo,
    __hip_bfloat16* __restrict__ vbo)
{
    __shared__ short As[128 * 64];
    __shared__ short Bs[64 * 64];
    int tid = threadIdx.x, lane = tid & 63;
    int w = tid >> 6, wr = w >> 1, wc = w & 1;
    int bm = blockIdx.x, bn = blockIdx.y;

    f32x4 acc[4][2];
    #pragma unroll
    for (int fm = 0; fm < 4; ++fm)
        #pragma unroll
        for (int fn = 0; fn < 2; ++fn) acc[fm][fn] = (f32x4)0.0f;

    for (int kt = 0; kt < CC; kt += 64) {
        #pragma unroll
        for (int r = 0; r < 4; ++r) {
            int off = r * 256 + tid;
            int row = off >> 3, ce = (off & 7) * 8;
            gload16(A + ((size_t)(bm * 128 + row) * CC + kt + ce), &As[off * 8]);
        }
        #pragma unroll
        for (int r = 0; r < 2; ++r) {
            int off = r * 256 + tid;
            int row = off >> 3, ce = (off & 7) * 8;
            gload16(Bw + ((size_t)(bn * 64 + row) * CC + kt + ce), &Bs[off * 8]);
        }
        __syncthreads();
        #pragma unroll
        for (int kk = 0; kk < 2; ++kk) {
            int kc = kk * 32 + (lane >> 4) * 8;
            bf16x8 af[4], bfr[2];
            #pragma unroll
            for (int fm = 0; fm < 4; ++fm)
                af[fm] = *(const bf16x8*)&As[(wr * 64 + fm * 16 + (lane & 15)) * 64 + kc];
            #pragma unroll
            for (int fn = 0; fn < 2; ++fn)
                bfr[fn] = *(const bf16x8*)&Bs[(wc * 32 + fn * 16 + (lane & 15)) * 64 + kc];
            #pragma unroll
            for (int fm = 0; fm < 4; ++fm)
                #pragma unroll
                for (int fn = 0; fn < 2; ++fn)
                    acc[fm][fn] = __builtin_amdgcn_mfma_f32_16x16x32_bf16(
                        af[fm], bfr[fn], acc[fm][fn], 0, 0, 0);
        }
        __syncthreads();
    }

    __hip_bfloat16* dst = (bn < 3) ? qbo : (bn < 6) ? kbo : vbo;
    int cbase = (bn % 3) * 64 + wc * 32;
    bool donorm = (bn < 6);
    bool isq = (bn < 3);
    float qscale = __expf(fminf(lscale[(bn % 3) * 2 + wc], 4.6051702f));
    int bcol = bn * 64 + wc * 32 + (lane & 15);
    #pragma unroll
    for (int fm = 0; fm < 4; ++fm)
        #pragma unroll
        for (int r = 0; r < 4; ++r) {
            float v0 = acc[fm][0][r] + bias[bcol];
            float v1 = acc[fm][1][r] + bias[bcol + 16];
            if (donorm) {
                float s2 = v0 * v0 + v1 * v1;
                s2 += __shfl_xor(s2, 1);
                s2 += __shfl_xor(s2, 2);
                s2 += __shfl_xor(s2, 4);
                s2 += __shfl_xor(s2, 8);
                float rn = rsqrtf(s2);
                if (isq) rn *= qscale;
                v0 *= rn; v1 *= rn;
            }
            int rowg = bm * 128 + wr * 64 + fm * 16 + ((lane >> 4) << 2) + r;
            dst[(size_t)rowg * CC + cbase + (lane & 15)] = __float2bfloat16(v0);
            dst[(size_t)rowg * CC + cbase + 16 + (lane & 15)] = __float2bfloat16(v1);
        }
}

// ---------------- MFMA attention: one block per (window, head), 4 waves x 64 q-rows ----------------
// St = mfma(K, Q) -> P rows lane-local by qrow=lane&31; P packed directly into PV A-frags;
// V read from transposed LDS with the SAME slot->j map so the permutation cancels.
#define VTP 260
__global__ __launch_bounds__(256, 2) void k_attn(
    const __hip_bfloat16* __restrict__ qb,
    const __hip_bfloat16* __restrict__ kb,
    const __hip_bfloat16* __restrict__ vb,
    const float* __restrict__ biasm,
    const float* __restrict__ lscale,
    __hip_bfloat16* __restrict__ ao)
{
    __shared__ short Vt[32 * VTP];
    int blk = blockIdx.x;
    int win = blk / NH, h = blk % NH;
    int wwh = (win >> 2) & 3, www = win & 3;
    int ty = (((wwh == 3) ? 2 : 0) | ((www == 3) ? 1 : 0));
    int tid = threadIdx.x;
    int wv = tid >> 6, lane = tid & 63;
    int c = lane & 31, g = lane >> 5;

    float scale = __expf(fminf(lscale[h], 4.6051702f));
    float M = scale + 16.0f;

    // ---- stage V transposed: Vt[d][j] ----
    {
        int j = wv * 64 + lane;
        const short* vsrc = (const short*)vb + ((size_t)(win * NN + j)) * CC + h * DD;
        #pragma unroll
        for (int q4 = 0; q4 < 4; ++q4) {
            bf16x8 t = *(const bf16x8*)(vsrc + q4 * 8);
            #pragma unroll
            for (int e = 0; e < 8; ++e)
                Vt[(q4 * 8 + e) * VTP + j] = t[e];
        }
    }
    __syncthreads();

    // ---- Q B-frags (held in regs for all tiles) ----
    const short* qsrc = (const short*)qb + ((size_t)(win * NN + wv * 64)) * CC + h * DD;
    bf16x8 qf[2][2];
    #pragma unroll
    for (int fq = 0; fq < 2; ++fq)
        #pragma unroll
        for (int kd = 0; kd < 2; ++kd)
            qf[fq][kd] = *(const bf16x8*)(qsrc + (size_t)(32 * fq + c) * CC + 16 * kd + 8 * g);

    f32x16 acc_o[2];
    acc_o[0] = (f32x16)0.0f; acc_o[1] = (f32x16)0.0f;
    float lsum[2] = {0.0f, 0.0f};

    const short* kbase = (const short*)kb + ((size_t)(win * NN)) * CC + h * DD;
    const float* bbase = biasm + (((size_t)ty * NH + h) * NN) * NN;

    for (int t = 0; t < 4; ++t) {
        int jt = t * 64;
        // K A-frags from global
        bf16x8 kf[2][2];
        #pragma unroll
        for (int fj = 0; fj < 2; ++fj)
            #pragma unroll
            for (int kd = 0; kd < 2; ++kd)
                kf[fj][kd] = *(const bf16x8*)(kbase + (size_t)(jt + 32 * fj + c) * CC + 16 * kd + 8 * g);
        // St = K @ Q^T  (C: col=qrow=lane&31, row=key rho(g,r))
        f32x16 st[2][2];
        #pragma unroll
        for (int fj = 0; fj < 2; ++fj)
            #pragma unroll
            for (int fq = 0; fq < 2; ++fq) {
                f32x16 tmp = __builtin_amdgcn_mfma_f32_32x32x16_bf16(
                    kf[fj][0], qf[fq][0], (f32x16)0.0f, 0, 0, 0);
                st[fj][fq] = __builtin_amdgcn_mfma_f32_32x32x16_bf16(
                    kf[fj][1], qf[fq][1], tmp, 0, 0, 0);
            }
        // bias + exp + row-sum + pack -> PV
        #pragma unroll
        for (int fj = 0; fj < 2; ++fj) {
            bf16x8 vfr[2];
            #pragma unroll
            for (int rb = 0; rb < 2; ++rb) {
                int j0 = jt + 32 * fj + 16 * rb + 4 * g;
                uint2 va = *(const uint2*)&Vt[c * VTP + j0];
                uint2 vb2 = *(const uint2*)&Vt[c * VTP + j0 + 8];
                union { unsigned u[4]; bf16x8 v; } vu;
                vu.u[0] = va.x; vu.u[1] = va.y; vu.u[2] = vb2.x; vu.u[3] = vb2.y;
                vfr[rb] = vu.v;
            }
            #pragma unroll
            for (int fq = 0; fq < 2; ++fq) {
                const float* bp = bbase + (size_t)(wv * 64 + 32 * fq + c) * NN + jt + 32 * fj + 4 * g;
                float4 b0 = *(const float4*)(bp);
                float4 b1 = *(const float4*)(bp + 8);
                float4 b2 = *(const float4*)(bp + 16);
                float4 b3 = *(const float4*)(bp + 24);
                float p[16];
                p[0]  = st[fj][fq][0]  + b0.x; p[1]  = st[fj][fq][1]  + b0.y;
                p[2]  = st[fj][fq][2]  + b0.z; p[3]  = st[fj][fq][3]  + b0.w;
                p[4]  = st[fj][fq][4]  + b1.x; p[5]  = st[fj][fq][5]  + b1.y;
                p[6]  = st[fj][fq][6]  + b1.z; p[7]  = st[fj][fq][7]  + b1.w;
                p[8]  = st[fj][fq][8]  + b2.x; p[9]  = st[fj][fq][9]  + b2.y;
                p[10] = st[fj][fq][10] + b2.z; p[11] = st[fj][fq][11] + b2.w;
                p[12] = st[fj][fq][12] + b3.x; p[13] = st[fj][fq][13] + b3.y;
                p[14] = st[fj][fq][14] + b3.z; p[15] = st[fj][fq][15] + b3.w;
                #pragma unroll
                for (int r = 0; r < 16; ++r) p[r] = __expf(p[r] - M);
                #pragma unroll
                for (int r = 0; r < 16; ++r) lsum[fq] += p[r];
                #pragma unroll
                for (int rb = 0; rb < 2; ++rb) {
                    union { unsigned u[4]; bf16x8 v; } pu;
                    pu.u[0] = pk2(p[8 * rb + 0], p[8 * rb + 1]);
                    pu.u[1] = pk2(p[8 * rb + 2], p[8 * rb + 3]);
                    pu.u[2] = pk2(p[8 * rb + 4], p[8 * rb + 5]);
                    pu.u[3] = pk2(p[8 * rb + 6], p[8 * rb + 7]);
                    acc_o[fq] = __builtin_amdgcn_mfma_f32_32x32x16_bf16(
                        pu.v, vfr[rb], acc_o[fq], 0, 0, 0);
                }
            }
        }
    }

    // ---- normalize + write ----
    #pragma unroll
    for (int fq = 0; fq < 2; ++fq) {
        lsum[fq] += __shfl_xor(lsum[fq], 32);
        float rlv = 1.0f / lsum[fq];
        #pragma unroll
        for (int r = 0; r < 16; ++r) {
            int rho = (r & 3) + 8 * (r >> 2) + 4 * g;
            float rli = __shfl(rlv, rho);
            int row = wv * 64 + 32 * fq + rho;
            ao[((size_t)(win * NN + row)) * CC + h * DD + c] =
                __float2bfloat16(acc_o[fq][r] * rli);
        }
    }
}

// ---------------- proj MFMA GEMM + window-reverse + cond-LN1 + residual ----------------
__global__ __launch_bounds__(256) void k_projgemm(
    const __hip_bfloat16* __restrict__ ao,
    const __hip_bfloat16* __restrict__ pwb,
    const float* __restrict__ pbias,
    const float* __restrict__ x, const float* __restrict__ time,
    const float* __restrict__ ww, const float* __restrict__ wb,
    const float* __restrict__ bw, const float* __restrict__ bb,
    float* __restrict__ hout, __hip_bfloat16* __restrict__ hb)
{
    __shared__ short As[128 * 64];
    __shared__ short Bs[192 * 64];
    __shared__ float part[128][4];
    int tid = threadIdx.x, lane = tid & 63;
    int w = tid >> 6, wr = w >> 1, wc = w & 1;
    int bm = blockIdx.x;

    f32x4 acc[4][6];
    #pragma unroll
    for (int fm = 0; fm < 4; ++fm)
        #pragma unroll
        for (int fn = 0; fn < 6; ++fn) acc[fm][fn] = (f32x4)0.0f;

    for (int kt = 0; kt < CC; kt += 64) {
        #pragma unroll
        for (int r = 0; r < 4; ++r) {
            int off = r * 256 + tid;
            int row = off >> 3, ce = (off & 7) * 8;
            gload16(ao + ((size_t)(bm * 128 + row) * CC + kt + ce), &As[off * 8]);
        }
        #pragma unroll
        for (int r = 0; r < 6; ++r) {
            int off = r * 256 + tid;
            int row = off >> 3, ce = (off & 7) * 8;
            gload16(pwb + ((size_t)row * CC + kt + ce), &Bs[off * 8]);
        }
        __syncthreads();
        #pragma unroll
        for (int kk = 0; kk < 2; ++kk) {
            int kc = kk * 32 + (lane >> 4) * 8;
            bf16x8 af[4], bfr[6];
            #pragma unroll
            for (int fm = 0; fm < 4; ++fm)
                af[fm] = *(const bf16x8*)&As[(wr * 64 + fm * 16 + (lane & 15)) * 64 + kc];
            #pragma unroll
            for (int fn = 0; fn < 6; ++fn)
                bfr[fn] = *(const bf16x8*)&Bs[(wc * 96 + fn * 16 + (lane & 15)) * 64 + kc];
            #pragma unroll
            for (int fm = 0; fm < 4; ++fm)
                #pragma unroll
                for (int fn = 0; fn < 6; ++fn)
                    acc[fm][fn] = __builtin_amdgcn_mfma_f32_16x16x32_bf16(
                        af[fm], bfr[fn], acc[fm][fn], 0, 0, 0);
        }
        __syncthreads();
    }

    // bias add + per-row LN partials (each wave owns 96 of 192 cols)
    #pragma unroll
    for (int fm = 0; fm < 4; ++fm)
        #pragma unroll
        for (int r = 0; r < 4; ++r) {
            float s = 0.0f, s2 = 0.0f;
            #pragma unroll
            for (int fn = 0; fn < 6; ++fn) {
                int col = wc * 96 + fn * 16 + (lane & 15);
                float v = acc[fm][fn][r] + pbias[col];
                acc[fm][fn][r] = v;
                s += v; s2 += v * v;
            }
            #pragma unroll
            for (int m = 1; m < 16; m <<= 1) {
                s  += __shfl_xor(s, m);
                s2 += __shfl_xor(s2, m);
            }
            if ((lane & 15) == 0) {
                int rl = wr * 64 + fm * 16 + ((lane >> 4) << 2) + r;
                part[rl][wc * 2]     = s;
                part[rl][wc * 2 + 1] = s2;
            }
        }
    __syncthreads();

    int win = bm >> 1;
    int b = win >> 4, wh = (win >> 2) & 3, wwn = win & 3;
    float tm = time[b];
    #pragma unroll
    for (int fm = 0; fm < 4; ++fm)
        #pragma unroll
        for (int r = 0; r < 4; ++r) {
            int rl = wr * 64 + fm * 16 + ((lane >> 4) << 2) + r;
            float s  = part[rl][0] + part[rl][2];
            float s2 = part[rl][1] + part[rl][3];
            float mean = s * (1.0f / 192.0f);
            float rstd = rsqrtf(s2 * (1.0f / 192.0f) - mean * mean + 1e-5f);
            int rw = bm * 128 + rl;
            int n = rw & 255;
            int yi = n >> 4, xi = n & 15;
            int y  = (wh * 16 + yi + SHIFT) & 63;
            int xq = (wwn * 16 + xi + SHIFT) & 63;
            size_t rimg = (size_t)b * 4096 + y * 64 + xq;
            #pragma unroll
            for (int fn = 0; fn < 6; ++fn) {
                int col = wc * 96 + fn * 16 + (lane & 15);
                float w_ = tm * ww[col] + wb[col];
                float b_ = tm * bw[col] + bb[col];
                float xn = (acc[fm][fn][r] - mean) * rstd;
                float hv = x[rimg * CC + col] + w_ * xn + b_;
                hout[rimg * CC + col] = hv;
                hb[rimg * CC + col] = __float2bfloat16(hv);
            }
        }
}

// ---------------- MFMA GEMM: C[M x N] = A[M x K] * W[N x K]^T (+bias, opt GELU) ----------------
template<int BN, int NWF, int EPI>
__global__ __launch_bounds__(256) void k_gemm(
    const __hip_bfloat16* __restrict__ A, const __hip_bfloat16* __restrict__ Bw,
    const float* __restrict__ bias, __hip_bfloat16* __restrict__ Cout,
    int K, int ldc)
{
    __shared__ short As[128 * 64];
    __shared__ short Bs[BN * 64];
    int tid = threadIdx.x;
    int lane = tid & 63;
    int w = tid >> 6, wr = w >> 1, wc = w & 1;
    int bm = blockIdx.x, bn = blockIdx.y;

    f32x4 acc[4][NWF];
    #pragma unroll
    for (int fm = 0; fm < 4; ++fm)
        #pragma unroll
        for (int fn = 0; fn < NWF; ++fn)
            acc[fm][fn] = (f32x4)0.0f;

    const int AR = (128 * 64) / (256 * 8);
    const int BR = (BN * 64) / (256 * 8);

    for (int kt = 0; kt < K; kt += 64) {
        #pragma unroll
        for (int r = 0; r < AR; ++r) {
            int off = r * 256 + tid;
            int row = off >> 3, ce = (off & 7) * 8;
            gload16(A + ((size_t)(bm * 128 + row) * K + kt + ce), &As[off * 8]);
        }
        #pragma unroll
        for (int r = 0; r < BR; ++r) {
            int off = r * 256 + tid;
            int row = off >> 3, ce = (off & 7) * 8;
            gload16(Bw + ((size_t)(bn * BN + row) * K + kt + ce), &Bs[off * 8]);
        }
        __syncthreads();
        #pragma unroll
        for (int kk = 0; kk < 2; ++kk) {
            int kc = kk * 32 + (lane >> 4) * 8;
            bf16x8 af[4], bfr[NWF];
            #pragma unroll
            for (int fm = 0; fm < 4; ++fm)
                af[fm] = *(const bf16x8*)&As[(wr * 64 + fm * 16 + (lane & 15)) * 64 + kc];
            #pragma unroll
            for (int fn = 0; fn < NWF; ++fn)
                bfr[fn] = *(const bf16x8*)&Bs[(wc * (BN / 2) + fn * 16 + (lane & 15)) * 64 + kc];
            #pragma unroll
            for (int fm = 0; fm < 4; ++fm)
                #pragma unroll
                for (int fn = 0; fn < NWF; ++fn)
                    acc[fm][fn] = __builtin_amdgcn_mfma_f32_16x16x32_bf16(
                        af[fm], bfr[fn], acc[fm][fn], 0, 0, 0);
        }
        __syncthreads();
    }

    #pragma unroll
    for (int fm = 0; fm < 4; ++fm)
        #pragma unroll
        for (int fn = 0; fn < NWF; ++fn)
            #pragma unroll
            for (int r = 0; r < 4; ++r) {
                int rowg = bm * 128 + wr * 64 + fm * 16 + ((lane >> 4) << 2) + r;
                int colg = bn * BN + wc * (BN / 2) + fn * 16 + (lane & 15);
                float v = acc[fm][fn][r] + bias[colg];
                if (EPI == 1) v = 0.5f * v * (1.0f + erff(v * 0.70710678f));
                Cout[(size_t)rowg * ldc + colg] = __float2bfloat16(v);
            }
}

// ---------------- cond-LN2 + residual, in-place on d_out (one wave per row) ----------------
__global__ __launch_bounds__(256) void k_ln2(
    const __hip_bfloat16* __restrict__ mlpb,
    float* __restrict__ hio, const float* __restrict__ time,
    const float* __restrict__ ww, const float* __restrict__ wb,
    const float* __restrict__ bw, const float* __restrict__ bb)
{
    int row = blockIdx.x * 4 + (threadIdx.x >> 6);
    int lane = threadIdx.x & 63;
    float v[3];
    float s = 0.0f, s2 = 0.0f;
    #pragma unroll
    for (int j = 0; j < 3; ++j) {
        v[j] = __bfloat162float(mlpb[(size_t)row * CC + lane + j * 64]);
        s += v[j]; s2 += v[j] * v[j];
    }
    #pragma unroll
    for (int m = 1; m < 64; m <<= 1) {
        s  += __shfl_xor(s, m, 64);
        s2 += __shfl_xor(s2, m, 64);
    }
    float mean = s * (1.0f / (float)CC);
    float rstd = rsqrtf(s2 * (1.0f / (float)CC) - mean * mean + 1e-5f);
    float tm = time[row >> 12];
    #pragma unroll
    for (int j = 0; j < 3; ++j) {
        int c = lane + j * 64;
        float w_ = tm * ww[c] + wb[c];
        float b_ = tm * bw[c] + bb[c];
        size_t o = (size_t)row * CC + c;
        hio[o] = hio[o] + w_ * ((v[j] - mean) * rstd) + b_;
    }
}

extern "C" void kernel_launch(void* const* d_in, const int* in_sizes, int n_in,
                              void* d_out, int out_size, void* d_ws, size_t ws_size,
                              hipStream_t stream)
{
    const float* x        = (const float*)d_in[0];
    const float* time     = (const float*)d_in[1];
    const float* q_w      = (const float*)d_in[2];
    const float* q_b      = (const float*)d_in[3];
    const float* k_w      = (const float*)d_in[4];
    const float* v_w      = (const float*)d_in[5];
    const float* v_b      = (const float*)d_in[6];
    const float* lscale   = (const float*)d_in[7];
    const float* cpb_w1   = (const float*)d_in[8];
    const float* cpb_b1   = (const float*)d_in[9];
    const float* cpb_w2   = (const float*)d_in[10];
    const float* proj_w   = (const float*)d_in[11];
    const float* proj_b   = (const float*)d_in[12];
    const float* ln1_ww   = (const float*)d_in[13];
    const float* ln1_wb   = (const float*)d_in[14];
    const float* ln1_bw   = (const float*)d_in[15];
    const float* ln1_bb   = (const float*)d_in[16];
    const float* fc1_w    = (const float*)d_in[17];
    const float* fc1_b    = (const float*)d_in[18];
    const float* fc2_w    = (const float*)d_in[19];
    const float* fc2_b    = (const float*)d_in[20];
    const float* ln2_ww   = (const float*)d_in[21];
    const float* ln2_wb   = (const float*)d_in[22];
    const float* ln2_bw   = (const float*)d_in[23];
    const float* ln2_bb   = (const float*)d_in[24];

    char* ws = (char*)d_ws;
    float* tbl            = (float*)(ws + OFF_TBL);
    float* biasm          = (float*)(ws + OFF_BIASM);
    __hip_bfloat16* wqkv  = (__hip_bfloat16*)(ws + OFF_WQKV);
    __hip_bfloat16* pwb   = (__hip_bfloat16*)(ws + OFF_PWB);
    __hip_bfloat16* w1b   = (__hip_bfloat16*)(ws + OFF_W1B);
    __hip_bfloat16* w2b   = (__hip_bfloat16*)(ws + OFF_W2B);
    float* bqkv           = (float*)(ws + OFF_BQKV);
    __hip_bfloat16* xb    = (__hip_bfloat16*)(ws + OFF_XB);
    __hip_bfloat16* qb    = (__hip_bfloat16*)(ws + OFF_Q);
    __hip_bfloat16* kb    = (__hip_bfloat16*)(ws + OFF_K);
    __hip_bfloat16* vb    = (__hip_bfloat16*)(ws + OFF_V);
    __hip_bfloat16* ao    = (__hip_bfloat16*)(ws + OFF_AO);
    __hip_bfloat16* hb    = (__hip_bfloat16*)(ws + OFF_HB);
    __hip_bfloat16* h2    = (__hip_bfloat16*)(ws + OFF_H2);
    __hip_bfloat16* mlpb  = (__hip_bfloat16*)(ws + OFF_MLP);
    float* out            = (float*)d_out;

    k_tbl   <<<961, 512, 0, stream>>>(cpb_w1, cpb_b1, cpb_w2, tbl);
    k_biasm <<<4 * NH * NN, 256, 0, stream>>>(tbl, biasm);
    k_cvt   <<<1731, 256, 0, stream>>>(q_w, k_w, v_w, proj_w, fc1_w, fc2_w,
                                       q_b, v_b, wqkv, pwb, w1b, w2b, bqkv);
    k_gather<<<12288, 256, 0, stream>>>(x, xb);
    k_qkvgemm<<<dim3(NROWS / 128, 9), 256, 0, stream>>>(xb, wqkv, bqkv, lscale, qb, kb, vb);
    k_attn  <<<NWIN * NH, 256, 0, stream>>>(qb, kb, vb, biasm, lscale, ao);
    k_projgemm<<<NROWS / 128, 256, 0, stream>>>(ao, pwb, proj_b, x, time,
                                                ln1_ww, ln1_wb, ln1_bw, ln1_bb, out, hb);
    k_gemm<128, 4, 1><<<dim3(NROWS / 128, HID / 128), 256, 0, stream>>>(
        hb, w1b, fc1_b, h2, CC, HID);
    k_gemm<64, 2, 2><<<dim3(NROWS / 128, CC / 64), 256, 0, stream>>>(
        h2, w2b, fc2_b, mlpb, HID, CC);
    k_ln2  <<<NROWS / 4, 256, 0, stream>>>(mlpb, out, time,
                                           ln2_ww, ln2_wb, ln2_bw, ln2_bb);
}